// Round 14
// baseline (667.393 us; speedup 1.0000x reference)
//
#include <hip/hip_runtime.h>
#include <hip/hip_bf16.h>

// N=12288, D=256. Single pass:
//   e=lrelu(u_i+v_j); q=exp2(e*log2e-SHIFT2) masked adj>0 (const shift, scale-free)
//   out_i = coef_i*(q_i@h_po) + 0.5*(adj_i@h_po),  coef_i=0.5*deg_i/denom_i
// fused14 = fused13 (producer/consumer specialization, counted producer vmcnt)
// with B moved OUT of LDS:
//   - consumers load B fragments straight from L2-resident bf16 h_poT
//     (SGPR-base + per-lane 32-bit offset; issued at step top, latency hidden
//     under the B-independent score phase; consumed before the barrier ->
//     plain __syncthreads stays free, ZERO consumer asm)
//   - the 3x rg-redundancy moves from the LDS pipe (was 96 of 144 b128/step)
//     to L1 (B step-tile = 32 KB = L1-sized)
//   - producers stage only adj+v: uniform 4 gl_lds/wave/step -> vmcnt(4)
//   - LDS 136 KB -> 49 KB

#define NN 12288
#define DD 256
#define BM 48
#define BK 64
#define NSTEPS (NN / BK)   // 192
#define VOFF 12288
#define BUFSZ 12544        // adj 12288 + v 256
#define LOG2E 1.44269504f
#define SHIFT2 36.067376f  // 25*log2e

typedef __attribute__((ext_vector_type(8))) short s16x8;
typedef __attribute__((ext_vector_type(4))) float f32x4;

__device__ __forceinline__ unsigned short f2bf(float f) {
  unsigned u = __builtin_bit_cast(unsigned, f);
  u += 0x7FFFu + ((u >> 16) & 1u);
  return (unsigned short)(u >> 16);
}
__device__ __forceinline__ unsigned pack_bf2(float a, float b) {
  unsigned short lo = __builtin_bit_cast(unsigned short, __float2bfloat16(a));
  unsigned short hi = __builtin_bit_cast(unsigned short, __float2bfloat16(b));
  return (unsigned)lo | ((unsigned)hi << 16);
}
__device__ __forceinline__ float exp2_hw(float x) {
  float r;
  asm("v_exp_f32 %0, %1" : "=v"(r) : "v"(x));
  return r;
}
__device__ __forceinline__ void gl_lds16(const void* g, void* l) {
  __builtin_amdgcn_global_load_lds(
      (const __attribute__((address_space(1))) void*)g,
      (__attribute__((address_space(3))) void*)l, 16, 0, 0);
}
__device__ __forceinline__ void gl_lds4(const void* g, void* l) {
  __builtin_amdgcn_global_load_lds(
      (const __attribute__((address_space(1))) void*)g,
      (__attribute__((address_space(3))) void*)l, 4, 0, 0);
}

// ---------------- prep: u2, v2 (pre-scaled by log2e) ----------------
__global__ __launch_bounds__(256) void prep_uv(
    const float* __restrict__ h_eu, const float* __restrict__ h_po,
    const float* __restrict__ h_lo, const float* __restrict__ a1,
    const float* __restrict__ a2, const float* __restrict__ a3,
    float* __restrict__ u, float* __restrict__ v) {
  const int t = threadIdx.x;
  const int wave = t >> 6, lane = t & 63;
  const int r0 = blockIdx.x * 64;
  for (int rr = 0; rr < 16; ++rr) {
    const int row = r0 + wave * 16 + rr;
    const float* pe = h_eu + (size_t)row * DD;
    const float* pl = h_lo + (size_t)row * DD;
    const float* pp = h_po + (size_t)row * DD;
    float su = 0.f, sv = 0.f;
#pragma unroll
    for (int c = 0; c < 4; ++c) {
      const int d = lane + c * 64;
      su = fmaf(pe[d], a1[d], su);
      su = fmaf(pl[d], a3[d], su);
      sv = fmaf(pp[d], a2[d], sv);
    }
#pragma unroll
    for (int m = 32; m; m >>= 1) {
      su += __shfl_xor(su, m, 64);
      sv += __shfl_xor(sv, m, 64);
    }
    if (lane == 0) { u[row] = su * LOG2E; v[row] = sv * LOG2E; }
  }
}

// ---------------- prep: h_poT (bf16, [D][N]) ----------------
__global__ __launch_bounds__(256) void prep_T(
    const float* __restrict__ hpo, unsigned short* __restrict__ h_poT) {
  const int t = threadIdx.x;
  const int r0 = blockIdx.x * 64;
  unsigned short* dst = h_poT + (size_t)t * NN + r0;
#pragma unroll
  for (int c = 0; c < 16; ++c) {
    unsigned short x0 = f2bf(hpo[(size_t)(r0 + c * 4 + 0) * DD + t]);
    unsigned short x1 = f2bf(hpo[(size_t)(r0 + c * 4 + 1) * DD + t]);
    unsigned short x2 = f2bf(hpo[(size_t)(r0 + c * 4 + 2) * DD + t]);
    unsigned short x3 = f2bf(hpo[(size_t)(r0 + c * 4 + 3) * DD + t]);
    ((uint2*)dst)[c] = make_uint2((unsigned)x0 | ((unsigned)x1 << 16),
                                  (unsigned)x2 | ((unsigned)x3 << 16));
  }
}

// ---------------- fused14 ----------------
__global__ __launch_bounds__(1024) void fused14(
    const float* __restrict__ adj, const float* __restrict__ u2,
    const float* __restrict__ v2, const unsigned short* __restrict__ h_poT,
    float* __restrict__ out) {
  __shared__ __align__(16) char sMem[49152];  // 3*BUFSZ=37632 staging; 48KB reduce
  __shared__ float sq[2][3][16], sa[2][3][16];

  const int t = threadIdx.x;
  const int w = t >> 6, lane = t & 63;
  const int lrow = lane & 15, kgrp = lane >> 4;
  const int i0 = blockIdx.x * BM;

  if (w < 12) {
    // ======================= CONSUMERS (waves 0..11) =======================
    const int rg = w >> 2;           // 0..2 row-group
    const int dh = (w >> 1) & 1;     // 0..1 D-half
    const int kh = w & 1;            // 0..1 k-slice
    const int row = i0 + rg * 16 + lrow;
    const float u_r = u2[row];
    const float uc1 = u_r - SHIFT2;
    const float uc2 = fmaf(0.01f, u_r, -SHIFT2);
    const int xr = (lrow & 7) << 4;

    const int aOff = (rg * 16 + lrow) * 256;
    const int kA0 = (kh * 128 + kgrp * 32) ^ xr;
    const int kA1 = (kh * 128 + kgrp * 32 + 16) ^ xr;
    const int vOff = VOFF + (kh * 32 + kgrp * 8) * 4;

    // B from global: uniform (SGPR) row bases + one per-lane byte offset
    const char* bbase[8];
#pragma unroll
    for (int dt = 0; dt < 8; ++dt)
      bbase[dt] = (const char*)h_poT + (size_t)(dh * 128 + dt * 16) * (NN * 2);
    unsigned boff = (unsigned)(lrow * NN + kh * 32 + kgrp * 8) * 2;

    f32x4 acc1[8] = {};  // q   @ B
    f32x4 acc2[8] = {};  // adj @ B
    float qsum = 0.f, asum = 0.f;

    __syncthreads();  // prologue: producers staged bufs 0,1

    int buf = 0;
    for (int s = 0; s < NSTEPS; ++s) {
      // issue B loads first (L2-hit latency hides under the score phase)
      uint4 b[8];
#pragma unroll
      for (int dt = 0; dt < 8; ++dt)
        b[dt] = *(const uint4*)(bbase[dt] + boff);
      boff += 128;

      const char* bufp = sMem + buf * BUFSZ;
      const f32x4 Vv0 = *(const f32x4*)(bufp + vOff);
      const f32x4 Vv1 = *(const f32x4*)(bufp + vOff + 16);
      const char* ab = bufp + aOff;
      const f32x4 A0 = *(const f32x4*)(ab + kA0);
      const f32x4 A1 = *(const f32x4*)(ab + kA1);
      const float af[8] = {A0[0], A0[1], A0[2], A0[3],
                           A1[0], A1[1], A1[2], A1[3]};
      const float vf[8] = {Vv0[0], Vv0[1], Vv0[2], Vv0[3],
                           Vv1[0], Vv1[1], Vv1[2], Vv1[3]};
      float qv[8];
#pragma unroll
      for (int e = 0; e < 8; ++e) {
        const float t1 = uc1 + vf[e];
        const float t2 = fmaf(0.01f, vf[e], uc2);
        float q = exp2_hw(fmaxf(t1, t2));
        q = (af[e] > 0.f) ? q : 0.f;
        qsum += q; asum += af[e]; qv[e] = q;
      }
      unsigned qp[4], ap[4];
#pragma unroll
      for (int e = 0; e < 4; ++e) {
        qp[e] = pack_bf2(qv[2 * e], qv[2 * e + 1]);
        ap[e] = pack_bf2(af[2 * e], af[2 * e + 1]);
      }
      const s16x8 qa = __builtin_bit_cast(s16x8, *(uint4*)qp);
      const s16x8 aa = __builtin_bit_cast(s16x8, *(uint4*)ap);
#pragma unroll
      for (int dt = 0; dt < 8; ++dt) {
        const s16x8 bb = __builtin_bit_cast(s16x8, b[dt]);
        acc1[dt] = __builtin_amdgcn_mfma_f32_16x16x32_bf16(qa, bb, acc1[dt], 0, 0, 0);
        acc2[dt] = __builtin_amdgcn_mfma_f32_16x16x32_bf16(aa, bb, acc2[dt], 0, 0, 0);
      }
      __syncthreads();  // consumers: B consumed, nothing outstanding -> free
      buf = (buf == 2) ? 0 : buf + 1;
    }

    // ---- stats ----
    qsum += __shfl_xor(qsum, 16, 64); qsum += __shfl_xor(qsum, 32, 64);
    asum += __shfl_xor(asum, 16, 64); asum += __shfl_xor(asum, 32, 64);
    if (dh == 0 && lane < 16) { sq[kh][rg][lane] = qsum; sa[kh][rg][lane] = asum; }
    __syncthreads();

    // ---- fold coef, reduce over kh via LDS (reuse sMem), write out ----
    f32x4 fin[8];
#pragma unroll
    for (int dt = 0; dt < 8; ++dt) {
#pragma unroll
      for (int g = 0; g < 4; ++g) {
        const int rr = kgrp * 4 + g;
        const float qq = sq[0][rg][rr] + sq[1][rg][rr];
        const float aa2 = sa[0][rg][rr] + sa[1][rg][rr];
        const float cfr = qq > 0.f ? 0.5f * aa2 / qq : 0.f;
        fin[dt][g] = cfr * acc1[dt][g] + 0.5f * acc2[dt][g];
      }
    }
    float* red = (float*)sMem;  // 48 KB reduce area
    const int rbase = ((rg * 2 + dh) * 8 * 64 + lane) * 4;
    if (kh == 1) {
#pragma unroll
      for (int dt = 0; dt < 8; ++dt) *(f32x4*)&red[rbase + dt * 256] = fin[dt];
    }
    __syncthreads();
    if (kh == 0) {
#pragma unroll
      for (int dt = 0; dt < 8; ++dt) {
        const f32x4 o = *(const f32x4*)&red[rbase + dt * 256];
        const int col = dh * 128 + dt * 16 + lrow;
#pragma unroll
        for (int g = 0; g < 4; ++g)
          out[(size_t)(i0 + rg * 16 + kgrp * 4 + g) * DD + col] = fin[dt][g] + o[g];
      }
    }
  } else {
    // ======================= PRODUCERS (waves 12..15) ======================
    const int pid = w - 12;  // 0..3
    // 3 adj staging ops (idx = pid*3+j in 0..11)
    const char* pA[3];
    int dA[3];
#pragma unroll
    for (int j = 0; j < 3; ++j) {
      const int idx = pid * 3 + j;
      pA[j] = (const char*)(adj + (size_t)(i0 + idx * 4 + (lane >> 4)) * NN)
              + (((lane & 15) ^ ((idx & 1) * 4 + (lane >> 4))) << 4);
      dA[j] = idx * 1024;
    }
    // v chunk: ALL producers load it (redundant same-byte writes, benign)
    // -> uniform 4 vmem ops per wave per step, exact per-wave vmcnt count.
    const float* pV = v2 + lane;

    // prologue: stage buffers 0 and 1 (steps 0,1); keep buf1's 4 in flight
#pragma unroll
    for (int b = 0; b < 2; ++b) {
      char* nb = sMem + b * BUFSZ;
#pragma unroll
      for (int j = 0; j < 3; ++j) { gl_lds16(pA[j], nb + dA[j]); pA[j] += 256; }
      gl_lds4(pV, nb + VOFF); pV += 64;
    }
    asm volatile("s_waitcnt vmcnt(4)" ::: "memory");  // buf0 resident
    __builtin_amdgcn_s_barrier();

    int nbuf = 2;
    for (int s = 0; s < NSTEPS; ++s) {
      if (s < NSTEPS - 2) {
        char* nb = sMem + nbuf * BUFSZ;
#pragma unroll
        for (int j = 0; j < 3; ++j) { gl_lds16(pA[j], nb + dA[j]); pA[j] += 256; }
        gl_lds4(pV, nb + VOFF); pV += 64;
        // drain step-(s+1)'s 4 loads; keep this step's 4 in flight
        asm volatile("s_waitcnt vmcnt(4)" ::: "memory");
      } else if (s == NSTEPS - 2) {
        asm volatile("s_waitcnt vmcnt(0)" ::: "memory");  // final buf resident
      }
      __builtin_amdgcn_s_barrier();
      nbuf = (nbuf == 2) ? 0 : nbuf + 1;
    }
    __syncthreads();  // match stats barrier
    __syncthreads();  // match reduce barrier
  }
}

// ---------------- fallback (small ws): round-2 proven kernel ----------------
__global__ __launch_bounds__(256) void fused_fb(
    const float* __restrict__ adj, const float* __restrict__ u,
    const float* __restrict__ v, const float* __restrict__ hpo,
    float* __restrict__ out) {
#define BMF 32
#define LDA 40
  __shared__ unsigned short qlds[BMF][LDA];
  __shared__ unsigned short alds[BMF][LDA];
  __shared__ unsigned short btf[DD][LDA];
  __shared__ float denom_s[BMF], deg_s[BMF], coef_s[BMF];

  const int t = threadIdx.x;
  const int wave = t >> 6, lane = t & 63;
  const int i0 = blockIdx.x * BMF;
  const int sr = t >> 3;
  const int sc = (t & 7) * 4;
  const float u_r = u[i0 + sr];
  const int d0 = wave * 64;
  const int lrow = lane & 15;
  const int kgrp = lane >> 4;

  f32x4 acc1[2][4] = {};
  f32x4 acc2[2][4] = {};
  float qsum = 0.f, asum = 0.f;

  const float* arow = adj + (size_t)(i0 + sr) * NN + sc;
  float4 a_cur = *(const float4*)(arow);

  constexpr int NSTEP = NN / 32;
  for (int jt = 0; jt < NSTEP; ++jt) {
    const int j = jt * 32;
    float4 a_nxt;
    const bool has_next = (jt + 1 < NSTEP);
    if (has_next) a_nxt = *(const float4*)(arow + j + 32);
    const float4 vv = *(const float4*)(v + j + sc);
    unsigned short qb[4], ab[4];
    {
      const float aa4[4] = {a_cur.x, a_cur.y, a_cur.z, a_cur.w};
      const float vvv[4] = {vv.x, vv.y, vv.z, vv.w};
#pragma unroll
      for (int k = 0; k < 4; ++k) {
        const float a = aa4[k];
        const float s = u_r + vvv[k];
        const float x = fmaxf(s, 0.01f * s);
        const float q = (a > 0.f) ? exp2_hw(x - SHIFT2) : 0.f;
        qsum += q;
        asum += a;
        qb[k] = f2bf(q);
        ab[k] = f2bf(a);
      }
    }
    *(uint2*)&qlds[sr][sc] = make_uint2((unsigned)qb[0] | ((unsigned)qb[1] << 16),
                                        (unsigned)qb[2] | ((unsigned)qb[3] << 16));
    *(uint2*)&alds[sr][sc] = make_uint2((unsigned)ab[0] | ((unsigned)ab[1] << 16),
                                        (unsigned)ab[2] | ((unsigned)ab[3] << 16));
    {
      const int br = t >> 3;
      const float* src = hpo + (size_t)(j + br) * DD;
#pragma unroll
      for (int cc = 0; cc < 8; ++cc) {
        const int c = (t & 7) * 4 + cc * 32;
        const float4 hv = *(const float4*)(src + c);
        btf[c + 0][br] = f2bf(hv.x);
        btf[c + 1][br] = f2bf(hv.y);
        btf[c + 2][br] = f2bf(hv.z);
        btf[c + 3][br] = f2bf(hv.w);
      }
    }
    __syncthreads();

    const s16x8 qa0 = *(const s16x8*)&qlds[lrow][kgrp * 8];
    const s16x8 qa1 = *(const s16x8*)&qlds[16 + lrow][kgrp * 8];
    const s16x8 ad0 = *(const s16x8*)&alds[lrow][kgrp * 8];
    const s16x8 ad1 = *(const s16x8*)&alds[16 + lrow][kgrp * 8];
#pragma unroll
    for (int dt = 0; dt < 4; ++dt) {
      const s16x8 b = *(const s16x8*)&btf[d0 + dt * 16 + lrow][kgrp * 8];
      acc1[0][dt] = __builtin_amdgcn_mfma_f32_16x16x32_bf16(qa0, b, acc1[0][dt], 0, 0, 0);
      acc1[1][dt] = __builtin_amdgcn_mfma_f32_16x16x32_bf16(qa1, b, acc1[1][dt], 0, 0, 0);
      acc2[0][dt] = __builtin_amdgcn_mfma_f32_16x16x32_bf16(ad0, b, acc2[0][dt], 0, 0, 0);
      acc2[1][dt] = __builtin_amdgcn_mfma_f32_16x16x32_bf16(ad1, b, acc2[1][dt], 0, 0, 0);
    }
    __syncthreads();
    if (has_next) a_cur = a_nxt;
  }
#pragma unroll
  for (int m = 1; m <= 4; m <<= 1) {
    qsum += __shfl_xor(qsum, m, 64);
    asum += __shfl_xor(asum, m, 64);
  }
  if ((t & 7) == 0) { denom_s[sr] = qsum; deg_s[sr] = asum; }
  __syncthreads();
  if (t < BMF) {
    const float dn = denom_s[t];
    coef_s[t] = dn > 0.f ? 0.5f * deg_s[t] / dn : 0.f;
  }
  __syncthreads();
#pragma unroll
  for (int f = 0; f < 2; ++f) {
#pragma unroll
    for (int dt = 0; dt < 4; ++dt) {
      const int col = d0 + dt * 16 + lrow;
#pragma unroll
      for (int g = 0; g < 4; ++g) {
        const int r = f * 16 + kgrp * 4 + g;
        out[(size_t)(i0 + r) * DD + col] =
            coef_s[r] * acc1[f][dt][g] + 0.5f * acc2[f][dt][g];
      }
    }
  }
}

extern "C" void kernel_launch(void* const* d_in, const int* in_sizes, int n_in,
                              void* d_out, int out_size, void* d_ws, size_t ws_size,
                              hipStream_t stream) {
  const float* h_eu = (const float*)d_in[0];
  const float* h_po = (const float*)d_in[1];
  const float* h_lo = (const float*)d_in[2];
  const float* adj  = (const float*)d_in[3];
  const float* a1   = (const float*)d_in[4];
  const float* a2   = (const float*)d_in[5];
  const float* a3   = (const float*)d_in[6];
  float* out = (float*)d_out;

  // ws layout: u[N] | v[N] | h_poT[D*N] bf16 = 6,389,760 B
  const size_t need_full = (size_t)2 * NN * 4 + (size_t)NN * DD * 2;
  float* u = (float*)d_ws;
  float* v = u + NN;
  unsigned short* h_poT = (unsigned short*)(v + NN);
  const bool big_ws = ws_size >= need_full;

  prep_uv<<<NN / 64, 256, 0, stream>>>(h_eu, h_po, h_lo, a1, a2, a3, u, v);
  if (big_ws) {
    prep_T<<<NN / 64, 256, 0, stream>>>(h_po, h_poT);
    fused14<<<NN / BM, 1024, 0, stream>>>(adj, u, v, h_poT, out);
  } else {
    fused_fb<<<NN / 32, 256, 0, stream>>>(adj, u, v, h_po, out);
  }
}

// Round 15
// 522.239 us; speedup vs baseline: 1.2779x; 1.2779x over previous
//
#include <hip/hip_runtime.h>
#include <hip/hip_bf16.h>

// N=12288, D=256. Single pass:
//   e=lrelu(u_i+v_j); q=exp2(e*log2e-SHIFT2) masked adj>0 (const shift, scale-free)
//   out_i = coef_i*(q_i@h_po) + 0.5*(adj_i@h_po),  coef_i=0.5*deg_i/denom_i
// fused15 = fused13 (253us total; producer/consumer specialization, counted
// producer vmcnt(12), 3-buffer depth-2) with M-REGISTER-BLOCKED consumers:
//   - 4 consumer waves (2dh x 2kh), each covers ALL 48 rows (m_rep=3)
//   - B read ONCE per (dh,kh): consumer ds_read 144 -> 64 per step (-55%)
//     (fused14 proved the redundancy must be ELIMINATED, not moved to L2)
//   - acc = 192 VGPR/wave; block 512 = 8 waves/CU -> 256-VGPR budget
//     (__launch_bounds__(512,2)); per-dt B transient (1 b128 -> 6 MFMA -> dead)
//   - producers byte-identical to fused13 (12 gl_lds/wave/step, vmcnt(12))

#define NN 12288
#define DD 256
#define BM 48
#define BK 64
#define NSTEPS (NN / BK)   // 192
#define BOFF 12288
#define VOFF 45056
#define BUFSZ 45312        // adj 12288 + B 32768 + v 256
#define LOG2E 1.44269504f
#define SHIFT2 36.067376f  // 25*log2e

typedef __attribute__((ext_vector_type(8))) short s16x8;
typedef __attribute__((ext_vector_type(4))) float f32x4;

__device__ __forceinline__ unsigned short f2bf(float f) {
  unsigned u = __builtin_bit_cast(unsigned, f);
  u += 0x7FFFu + ((u >> 16) & 1u);
  return (unsigned short)(u >> 16);
}
__device__ __forceinline__ unsigned pack_bf2(float a, float b) {
  unsigned short lo = __builtin_bit_cast(unsigned short, __float2bfloat16(a));
  unsigned short hi = __builtin_bit_cast(unsigned short, __float2bfloat16(b));
  return (unsigned)lo | ((unsigned)hi << 16);
}
__device__ __forceinline__ float exp2_hw(float x) {
  float r;
  asm("v_exp_f32 %0, %1" : "=v"(r) : "v"(x));
  return r;
}
__device__ __forceinline__ void gl_lds16(const void* g, void* l) {
  __builtin_amdgcn_global_load_lds(
      (const __attribute__((address_space(1))) void*)g,
      (__attribute__((address_space(3))) void*)l, 16, 0, 0);
}
__device__ __forceinline__ void gl_lds4(const void* g, void* l) {
  __builtin_amdgcn_global_load_lds(
      (const __attribute__((address_space(1))) void*)g,
      (__attribute__((address_space(3))) void*)l, 4, 0, 0);
}

// ---------------- prep: u2, v2 (pre-scaled by log2e) ----------------
__global__ __launch_bounds__(256) void prep_uv(
    const float* __restrict__ h_eu, const float* __restrict__ h_po,
    const float* __restrict__ h_lo, const float* __restrict__ a1,
    const float* __restrict__ a2, const float* __restrict__ a3,
    float* __restrict__ u, float* __restrict__ v) {
  const int t = threadIdx.x;
  const int wave = t >> 6, lane = t & 63;
  const int r0 = blockIdx.x * 64;
  for (int rr = 0; rr < 16; ++rr) {
    const int row = r0 + wave * 16 + rr;
    const float* pe = h_eu + (size_t)row * DD;
    const float* pl = h_lo + (size_t)row * DD;
    const float* pp = h_po + (size_t)row * DD;
    float su = 0.f, sv = 0.f;
#pragma unroll
    for (int c = 0; c < 4; ++c) {
      const int d = lane + c * 64;
      su = fmaf(pe[d], a1[d], su);
      su = fmaf(pl[d], a3[d], su);
      sv = fmaf(pp[d], a2[d], sv);
    }
#pragma unroll
    for (int m = 32; m; m >>= 1) {
      su += __shfl_xor(su, m, 64);
      sv += __shfl_xor(sv, m, 64);
    }
    if (lane == 0) { u[row] = su * LOG2E; v[row] = sv * LOG2E; }
  }
}

// ---------------- prep: h_poT (bf16, [D][N]) ----------------
__global__ __launch_bounds__(256) void prep_T(
    const float* __restrict__ hpo, unsigned short* __restrict__ h_poT) {
  const int t = threadIdx.x;
  const int r0 = blockIdx.x * 64;
  unsigned short* dst = h_poT + (size_t)t * NN + r0;
#pragma unroll
  for (int c = 0; c < 16; ++c) {
    unsigned short x0 = f2bf(hpo[(size_t)(r0 + c * 4 + 0) * DD + t]);
    unsigned short x1 = f2bf(hpo[(size_t)(r0 + c * 4 + 1) * DD + t]);
    unsigned short x2 = f2bf(hpo[(size_t)(r0 + c * 4 + 2) * DD + t]);
    unsigned short x3 = f2bf(hpo[(size_t)(r0 + c * 4 + 3) * DD + t]);
    ((uint2*)dst)[c] = make_uint2((unsigned)x0 | ((unsigned)x1 << 16),
                                  (unsigned)x2 | ((unsigned)x3 << 16));
  }
}

// ---------------- fused15 ----------------
__global__ __launch_bounds__(512, 2) void fused15(
    const float* __restrict__ adj, const float* __restrict__ u2,
    const float* __restrict__ v2, const unsigned short* __restrict__ h_poT,
    float* __restrict__ out) {
  __shared__ __align__(16) char sMem[3 * BUFSZ];  // 135,936 B
  __shared__ float sq[2][3][16], sa[2][3][16];

  const int t = threadIdx.x;
  const int w = t >> 6, lane = t & 63;
  const int lrow = lane & 15, kgrp = lane >> 4;
  const int i0 = blockIdx.x * BM;

  if (w < 4) {
    // ========== CONSUMERS (waves 0..3): m_rep=3, dh x kh ==========
    const int dh = w >> 1;           // 0..1 D-half (128 cols)
    const int kh = w & 1;            // 0..1 k-slice (32 of 64)
    const int xr = (lrow & 7) << 4;

    float uc1[3], uc2[3];
#pragma unroll
    for (int m = 0; m < 3; ++m) {
      const float ur = u2[i0 + m * 16 + lrow];
      uc1[m] = ur - SHIFT2;
      uc2[m] = fmaf(0.01f, ur, -SHIFT2);
    }

    const int aOff0 = lrow * 256;                        // + m*4096
    const int kA0 = (kh * 128 + kgrp * 32) ^ xr;
    const int kA1 = (kh * 128 + kgrp * 32 + 16) ^ xr;
    const int bOff = BOFF + (dh * 128 + lrow) * 128 + ((kh * 64 + kgrp * 16) ^ xr);
    const int vOff = VOFF + (kh * 32 + kgrp * 8) * 4;

    f32x4 acc1[3][8] = {};  // q   @ B   (m x dt)
    f32x4 acc2[3][8] = {};  // adj @ B
    float qsum[3] = {0.f, 0.f, 0.f}, asum[3] = {0.f, 0.f, 0.f};

    __syncthreads();  // prologue: producers staged bufs 0,1

    int buf = 0;
    for (int s = 0; s < NSTEPS; ++s) {
      const char* bufp = sMem + buf * BUFSZ;
      const f32x4 Vv0 = *(const f32x4*)(bufp + vOff);
      const f32x4 Vv1 = *(const f32x4*)(bufp + vOff + 16);
      const float vf[8] = {Vv0[0], Vv0[1], Vv0[2], Vv0[3],
                           Vv1[0], Vv1[1], Vv1[2], Vv1[3]};

      s16x8 qa[3], aa[3];
#pragma unroll
      for (int m = 0; m < 3; ++m) {
        const char* ab = bufp + aOff0 + m * 4096;
        const f32x4 A0 = *(const f32x4*)(ab + kA0);
        const f32x4 A1 = *(const f32x4*)(ab + kA1);
        const float af[8] = {A0[0], A0[1], A0[2], A0[3],
                             A1[0], A1[1], A1[2], A1[3]};
        float qv[8];
#pragma unroll
        for (int e = 0; e < 8; ++e) {
          const float t1 = uc1[m] + vf[e];
          const float t2 = fmaf(0.01f, vf[e], uc2[m]);
          float q = exp2_hw(fmaxf(t1, t2));
          q = (af[e] > 0.f) ? q : 0.f;
          qsum[m] += q; asum[m] += af[e]; qv[e] = q;
        }
        unsigned qp[4], ap[4];
#pragma unroll
        for (int e = 0; e < 4; ++e) {
          qp[e] = pack_bf2(qv[2 * e], qv[2 * e + 1]);
          ap[e] = pack_bf2(af[2 * e], af[2 * e + 1]);
        }
        qa[m] = __builtin_bit_cast(s16x8, *(uint4*)qp);
        aa[m] = __builtin_bit_cast(s16x8, *(uint4*)ap);
      }

      const char* bb = bufp + bOff;
#pragma unroll
      for (int dt = 0; dt < 8; ++dt) {
        const s16x8 b = *(const s16x8*)(bb + dt * 2048);  // read once, 6 MFMAs
#pragma unroll
        for (int m = 0; m < 3; ++m) {
          acc1[m][dt] = __builtin_amdgcn_mfma_f32_16x16x32_bf16(qa[m], b, acc1[m][dt], 0, 0, 0);
          acc2[m][dt] = __builtin_amdgcn_mfma_f32_16x16x32_bf16(aa[m], b, acc2[m][dt], 0, 0, 0);
        }
      }
      __syncthreads();  // consumers: no outstanding vmem -> free wait
      buf = (buf == 2) ? 0 : buf + 1;
    }

    // ---- stats: reduce over kgrp, publish per (kh, m, row) ----
#pragma unroll
    for (int m = 0; m < 3; ++m) {
      qsum[m] += __shfl_xor(qsum[m], 16, 64);
      qsum[m] += __shfl_xor(qsum[m], 32, 64);
      asum[m] += __shfl_xor(asum[m], 16, 64);
      asum[m] += __shfl_xor(asum[m], 32, 64);
    }
    if (dh == 0 && lane < 16) {
#pragma unroll
      for (int m = 0; m < 3; ++m) {
        sq[kh][m][lane] = qsum[m];
        sa[kh][m][lane] = asum[m];
      }
    }
    __syncthreads();

    // ---- fold coef, reduce over kh via LDS (reuse sMem), write out ----
    float* red = (float*)sMem;  // [dh*24 + m*8 + dt][lane][4] f32 = 48 KB
    if (kh == 1) {
#pragma unroll
      for (int m = 0; m < 3; ++m) {
#pragma unroll
        for (int dt = 0; dt < 8; ++dt) {
          f32x4 fin;
#pragma unroll
          for (int g = 0; g < 4; ++g) {
            const int rr = kgrp * 4 + g;
            const float qq = sq[0][m][rr] + sq[1][m][rr];
            const float aa2 = sa[0][m][rr] + sa[1][m][rr];
            const float cfr = qq > 0.f ? 0.5f * aa2 / qq : 0.f;
            fin[g] = cfr * acc1[m][dt][g] + 0.5f * acc2[m][dt][g];
          }
          *(f32x4*)&red[(((dh * 3 + m) * 8 + dt) * 64 + lane) * 4] = fin;
        }
      }
    }
    __syncthreads();
    if (kh == 0) {
#pragma unroll
      for (int m = 0; m < 3; ++m) {
#pragma unroll
        for (int dt = 0; dt < 8; ++dt) {
          const f32x4 o = *(const f32x4*)&red[(((dh * 3 + m) * 8 + dt) * 64 + lane) * 4];
          const int col = dh * 128 + dt * 16 + lrow;
#pragma unroll
          for (int g = 0; g < 4; ++g) {
            const int rr = kgrp * 4 + g;
            const float qq = sq[0][m][rr] + sq[1][m][rr];
            const float aa2 = sa[0][m][rr] + sa[1][m][rr];
            const float cfr = qq > 0.f ? 0.5f * aa2 / qq : 0.f;
            out[(size_t)(i0 + m * 16 + rr) * DD + col] =
                cfr * acc1[m][dt][g] + 0.5f * acc2[m][dt][g] + o[g];
          }
        }
      }
    }
  } else {
    // ========== PRODUCERS (waves 4..7): byte-identical to fused13 ==========
    const int pid = w - 4;  // 0..3
    const char* pA[3];
    int dA[3];
#pragma unroll
    for (int j = 0; j < 3; ++j) {
      const int idx = pid * 3 + j;
      pA[j] = (const char*)(adj + (size_t)(i0 + idx * 4 + (lane >> 4)) * NN)
              + (((lane & 15) ^ ((idx & 1) * 4 + (lane >> 4))) << 4);
      dA[j] = idx * 1024;
    }
    const int ko = ((lane & 7) ^ (lane >> 3)) << 4;
    const char* pB[8];
    int dB[8];
#pragma unroll
    for (int j = 0; j < 8; ++j) {
      const int ib = pid * 8 + j;
      pB[j] = (const char*)h_poT + (size_t)(ib * 8 + (lane >> 3)) * (NN * 2) + ko;
      dB[j] = BOFF + ib * 1024;
    }
    // v chunk: ALL producers load it (redundant same-byte writes, benign)
    // -> uniform 12 vmem ops per wave per step, exact per-wave vmcnt count.
    const float* pV = v2 + lane;

    // prologue: stage buffers 0 and 1 (steps 0,1); keep buf1's 12 in flight
#pragma unroll
    for (int b = 0; b < 2; ++b) {
      char* nb = sMem + b * BUFSZ;
#pragma unroll
      for (int j = 0; j < 3; ++j) { gl_lds16(pA[j], nb + dA[j]); pA[j] += 256; }
#pragma unroll
      for (int j = 0; j < 8; ++j) { gl_lds16(pB[j], nb + dB[j]); pB[j] += 128; }
      gl_lds4(pV, nb + VOFF); pV += 64;
    }
    asm volatile("s_waitcnt vmcnt(12)" ::: "memory");  // buf0 resident
    __builtin_amdgcn_s_barrier();

    int nbuf = 2;
    for (int s = 0; s < NSTEPS; ++s) {
      if (s < NSTEPS - 2) {
        char* nb = sMem + nbuf * BUFSZ;
#pragma unroll
        for (int j = 0; j < 3; ++j) { gl_lds16(pA[j], nb + dA[j]); pA[j] += 256; }
#pragma unroll
        for (int j = 0; j < 8; ++j) { gl_lds16(pB[j], nb + dB[j]); pB[j] += 128; }
        gl_lds4(pV, nb + VOFF); pV += 64;
        // drain step-(s+1)'s 12 loads; keep this step's 12 in flight
        asm volatile("s_waitcnt vmcnt(12)" ::: "memory");
      } else if (s == NSTEPS - 2) {
        asm volatile("s_waitcnt vmcnt(0)" ::: "memory");  // final buf resident
      }
      __builtin_amdgcn_s_barrier();
      nbuf = (nbuf == 2) ? 0 : nbuf + 1;
    }
    __syncthreads();  // match stats barrier
    __syncthreads();  // match reduce barrier
  }
}

// ---------------- fallback (small ws): round-2 proven kernel ----------------
__global__ __launch_bounds__(256) void fused_fb(
    const float* __restrict__ adj, const float* __restrict__ u,
    const float* __restrict__ v, const float* __restrict__ hpo,
    float* __restrict__ out) {
#define BMF 32
#define LDA 40
  __shared__ unsigned short qlds[BMF][LDA];
  __shared__ unsigned short alds[BMF][LDA];
  __shared__ unsigned short btf[DD][LDA];
  __shared__ float denom_s[BMF], deg_s[BMF], coef_s[BMF];

  const int t = threadIdx.x;
  const int wave = t >> 6, lane = t & 63;
  const int i0 = blockIdx.x * BMF;
  const int sr = t >> 3;
  const int sc = (t & 7) * 4;
  const float u_r = u[i0 + sr];
  const int d0 = wave * 64;
  const int lrow = lane & 15;
  const int kgrp = lane >> 4;

  f32x4 acc1[2][4] = {};
  f32x4 acc2[2][4] = {};
  float qsum = 0.f, asum = 0.f;

  const float* arow = adj + (size_t)(i0 + sr) * NN + sc;
  float4 a_cur = *(const float4*)(arow);

  constexpr int NSTEP = NN / 32;
  for (int jt = 0; jt < NSTEP; ++jt) {
    const int j = jt * 32;
    float4 a_nxt;
    const bool has_next = (jt + 1 < NSTEP);
    if (has_next) a_nxt = *(const float4*)(arow + j + 32);
    const float4 vv = *(const float4*)(v + j + sc);
    unsigned short qb[4], ab[4];
    {
      const float aa4[4] = {a_cur.x, a_cur.y, a_cur.z, a_cur.w};
      const float vvv[4] = {vv.x, vv.y, vv.z, vv.w};
#pragma unroll
      for (int k = 0; k < 4; ++k) {
        const float a = aa4[k];
        const float s = u_r + vvv[k];
        const float x = fmaxf(s, 0.01f * s);
        const float q = (a > 0.f) ? exp2_hw(x - SHIFT2) : 0.f;
        qsum += q;
        asum += a;
        qb[k] = f2bf(q);
        ab[k] = f2bf(a);
      }
    }
    *(uint2*)&qlds[sr][sc] = make_uint2((unsigned)qb[0] | ((unsigned)qb[1] << 16),
                                        (unsigned)qb[2] | ((unsigned)qb[3] << 16));
    *(uint2*)&alds[sr][sc] = make_uint2((unsigned)ab[0] | ((unsigned)ab[1] << 16),
                                        (unsigned)ab[2] | ((unsigned)ab[3] << 16));
    {
      const int br = t >> 3;
      const float* src = hpo + (size_t)(j + br) * DD;
#pragma unroll
      for (int cc = 0; cc < 8; ++cc) {
        const int c = (t & 7) * 4 + cc * 32;
        const float4 hv = *(const float4*)(src + c);
        btf[c + 0][br] = f2bf(hv.x);
        btf[c + 1][br] = f2bf(hv.y);
        btf[c + 2][br] = f2bf(hv.z);
        btf[c + 3][br] = f2bf(hv.w);
      }
    }
    __syncthreads();

    const s16x8 qa0 = *(const s16x8*)&qlds[lrow][kgrp * 8];
    const s16x8 qa1 = *(const s16x8*)&qlds[16 + lrow][kgrp * 8];
    const s16x8 ad0 = *(const s16x8*)&alds[lrow][kgrp * 8];
    const s16x8 ad1 = *(const s16x8*)&alds[16 + lrow][kgrp * 8];
#pragma unroll
    for (int dt = 0; dt < 4; ++dt) {
      const s16x8 b = *(const s16x8*)&btf[d0 + dt * 16 + lrow][kgrp * 8];
      acc1[0][dt] = __builtin_amdgcn_mfma_f32_16x16x32_bf16(qa0, b, acc1[0][dt], 0, 0, 0);
      acc1[1][dt] = __builtin_amdgcn_mfma_f32_16x16x32_bf16(qa1, b, acc1[1][dt], 0, 0, 0);
      acc2[0][dt] = __builtin_amdgcn_mfma_f32_16x16x32_bf16(ad0, b, acc2[0][dt], 0, 0, 0);
      acc2[1][dt] = __builtin_amdgcn_mfma_f32_16x16x32_bf16(ad1, b, acc2[1][dt], 0, 0, 0);
    }
    __syncthreads();
    if (has_next) a_cur = a_nxt;
  }
#pragma unroll
  for (int m = 1; m <= 4; m <<= 1) {
    qsum += __shfl_xor(qsum, m, 64);
    asum += __shfl_xor(asum, m, 64);
  }
  if ((t & 7) == 0) { denom_s[sr] = qsum; deg_s[sr] = asum; }
  __syncthreads();
  if (t < BMF) {
    const float dn = denom_s[t];
    coef_s[t] = dn > 0.f ? 0.5f * deg_s[t] / dn : 0.f;
  }
  __syncthreads();
#pragma unroll
  for (int f = 0; f < 2; ++f) {
#pragma unroll
    for (int dt = 0; dt < 4; ++dt) {
      const int col = d0 + dt * 16 + lrow;
#pragma unroll
      for (int g = 0; g < 4; ++g) {
        const int r = f * 16 + kgrp * 4 + g;
        out[(size_t)(i0 + r) * DD + col] =
            coef_s[r] * acc1[f][dt][g] + 0.5f * acc2[f][dt][g];
      }
    }
  }
}

extern "C" void kernel_launch(void* const* d_in, const int* in_sizes, int n_in,
                              void* d_out, int out_size, void* d_ws, size_t ws_size,
                              hipStream_t stream) {
  const float* h_eu = (const float*)d_in[0];
  const float* h_po = (const float*)d_in[1];
  const float* h_lo = (const float*)d_in[2];
  const float* adj  = (const float*)d_in[3];
  const float* a1   = (const float*)d_in[4];
  const float* a2   = (const float*)d_in[5];
  const float* a3   = (const float*)d_in[6];
  float* out = (float*)d_out;

  // ws layout: u[N] | v[N] | h_poT[D*N] bf16 = 6,389,760 B
  const size_t need_full = (size_t)2 * NN * 4 + (size_t)NN * DD * 2;
  float* u = (float*)d_ws;
  float* v = u + NN;
  unsigned short* h_poT = (unsigned short*)(v + NN);
  const bool big_ws = ws_size >= need_full;

  prep_uv<<<NN / 64, 256, 0, stream>>>(h_eu, h_po, h_lo, a1, a2, a3, u, v);
  if (big_ws) {
    prep_T<<<NN / 64, 256, 0, stream>>>(h_po, h_poT);
    fused15<<<NN / BM, 512, 0, stream>>>(adj, u, v, h_poT, out);
  } else {
    fused_fb<<<NN / 32, 256, 0, stream>>>(adj, u, v, h_po, out);
  }
}

// Round 16
// 336.356 us; speedup vs baseline: 1.9842x; 1.5526x over previous
//
#include <hip/hip_runtime.h>
#include <hip/hip_bf16.h>

// N=12288, D=256. Single pass:
//   e=lrelu(u_i+v_j); q=exp2(e*log2e-SHIFT2) masked adj>0 (const shift, scale-free)
//   out_i = coef_i*(q_i@h_po) + 0.5*(adj_i@h_po),  coef_i=0.5*deg_i/denom_i
// fused16: SCORER-PRODUCER architecture.
//   4 producer waves: adj fp32 -> REGISTERS (3 dwordx4/lane, coalesced),
//     score ONCE (no dh/dq duplication), pack bf16 q/adj tiles -> ds_write_b64
//     (swizzled; writer controls addr), accumulate qsum/deg per-row in regs
//     (fixed row per (lane,j)), B staged via gl_lds (fused13's 8/wave).
//     Barrier = lgkmcnt(0)+s_barrier; the compiler's auto-wait on adj regs
//     retires the previous step's B gl_lds (in-order retirement, m135).
//   8 consumer waves (4 dq x 2 kh), m_rep=3, dual-mat: acc=96 regs (fits,
//     fused15's 192 spilled), 10 ds_read_b128/step (3q+3a+4B; B read ONCE
//     per (dq,kh)), zero VALU score, zero vmem -> free __syncthreads.
// Block LDS reads/step: 144 (fused13) -> ~80. HBM floor 1200 cy/step binds.

#define NN 12288
#define DD 256
#define BM 48
#define BK 64
#define NSTEPS (NN / BK)   // 192
#define QOFF 32768
#define AOFF 38912         // QOFF + 6144
#define BUFSZ2 45056       // B 32768 + q 6144 + a 6144
#define LOG2E 1.44269504f
#define SHIFT2 36.067376f  // 25*log2e

typedef __attribute__((ext_vector_type(8))) short s16x8;
typedef __attribute__((ext_vector_type(4))) float f32x4;

__device__ __forceinline__ unsigned short f2bf(float f) {
  unsigned u = __builtin_bit_cast(unsigned, f);
  u += 0x7FFFu + ((u >> 16) & 1u);
  return (unsigned short)(u >> 16);
}
__device__ __forceinline__ unsigned pack_bf2(float a, float b) {
  unsigned short lo = __builtin_bit_cast(unsigned short, __float2bfloat16(a));
  unsigned short hi = __builtin_bit_cast(unsigned short, __float2bfloat16(b));
  return (unsigned)lo | ((unsigned)hi << 16);
}
__device__ __forceinline__ float exp2_hw(float x) {
  float r;
  asm("v_exp_f32 %0, %1" : "=v"(r) : "v"(x));
  return r;
}
__device__ __forceinline__ void gl_lds16(const void* g, void* l) {
  __builtin_amdgcn_global_load_lds(
      (const __attribute__((address_space(1))) void*)g,
      (__attribute__((address_space(3))) void*)l, 16, 0, 0);
}

// ---------------- prep: u2, v2 (pre-scaled by log2e) ----------------
__global__ __launch_bounds__(256) void prep_uv(
    const float* __restrict__ h_eu, const float* __restrict__ h_po,
    const float* __restrict__ h_lo, const float* __restrict__ a1,
    const float* __restrict__ a2, const float* __restrict__ a3,
    float* __restrict__ u, float* __restrict__ v) {
  const int t = threadIdx.x;
  const int wave = t >> 6, lane = t & 63;
  const int r0 = blockIdx.x * 64;
  for (int rr = 0; rr < 16; ++rr) {
    const int row = r0 + wave * 16 + rr;
    const float* pe = h_eu + (size_t)row * DD;
    const float* pl = h_lo + (size_t)row * DD;
    const float* pp = h_po + (size_t)row * DD;
    float su = 0.f, sv = 0.f;
#pragma unroll
    for (int c = 0; c < 4; ++c) {
      const int d = lane + c * 64;
      su = fmaf(pe[d], a1[d], su);
      su = fmaf(pl[d], a3[d], su);
      sv = fmaf(pp[d], a2[d], sv);
    }
#pragma unroll
    for (int m = 32; m; m >>= 1) {
      su += __shfl_xor(su, m, 64);
      sv += __shfl_xor(sv, m, 64);
    }
    if (lane == 0) { u[row] = su * LOG2E; v[row] = sv * LOG2E; }
  }
}

// ---------------- prep: h_poT (bf16, [D][N]) ----------------
__global__ __launch_bounds__(256) void prep_T(
    const float* __restrict__ hpo, unsigned short* __restrict__ h_poT) {
  const int t = threadIdx.x;
  const int r0 = blockIdx.x * 64;
  unsigned short* dst = h_poT + (size_t)t * NN + r0;
#pragma unroll
  for (int c = 0; c < 16; ++c) {
    unsigned short x0 = f2bf(hpo[(size_t)(r0 + c * 4 + 0) * DD + t]);
    unsigned short x1 = f2bf(hpo[(size_t)(r0 + c * 4 + 1) * DD + t]);
    unsigned short x2 = f2bf(hpo[(size_t)(r0 + c * 4 + 2) * DD + t]);
    unsigned short x3 = f2bf(hpo[(size_t)(r0 + c * 4 + 3) * DD + t]);
    ((uint2*)dst)[c] = make_uint2((unsigned)x0 | ((unsigned)x1 << 16),
                                  (unsigned)x2 | ((unsigned)x3 << 16));
  }
}

// ---------------- fused16 ----------------
__global__ __launch_bounds__(768, 3) void fused16(
    const float* __restrict__ adj, const float* __restrict__ u2,
    const float* __restrict__ v2, const unsigned short* __restrict__ h_poT,
    float* __restrict__ out) {
  __shared__ __align__(16) char sMem[3 * BUFSZ2];  // 135,168 B
  __shared__ float sq[BM], sa[BM];

  const int t = threadIdx.x;
  const int w = t >> 6, lane = t & 63;
  const int lrow = lane & 15, kgrp = lane >> 4;
  const int i0 = blockIdx.x * BM;

  if (w < 8) {
    // ========== CONSUMERS (waves 0..7): pure GEMM, 4 dq x 2 kh, m_rep=3 =====
    const int dq = w >> 1;           // 0..3 D-quarter (64 cols)
    const int kh = w & 1;            // 0..1 k-slice (32 of 64)
    const int xr = (lrow & 7) << 4;
    const int kSel = (kh * 64 + kgrp * 16) ^ xr;
    const int bBase0 = (dq * 64 + lrow) * 128 + kSel;   // + dt*2048
    const int qBase0 = QOFF + lrow * 128 + kSel;        // + m*2048
    const int aBase0 = AOFF + lrow * 128 + kSel;

    f32x4 acc1[3][4] = {};  // q   @ B   (m x dt)
    f32x4 acc2[3][4] = {};  // adj @ B

    __syncthreads();  // prologue: producers staged buf0 tiles + B

    int buf = 0;
    for (int s = 0; s < NSTEPS; ++s) {
      const char* bufp = sMem + buf * BUFSZ2;
      uint4 b[4];
#pragma unroll
      for (int dt = 0; dt < 4; ++dt)
        b[dt] = *(const uint4*)(bufp + bBase0 + dt * 2048);
#pragma unroll
      for (int m = 0; m < 3; ++m) {
        const s16x8 qa = *(const s16x8*)(bufp + qBase0 + m * 2048);
        const s16x8 aa = *(const s16x8*)(bufp + aBase0 + m * 2048);
#pragma unroll
        for (int dt = 0; dt < 4; ++dt) {
          const s16x8 bb = __builtin_bit_cast(s16x8, b[dt]);
          acc1[m][dt] = __builtin_amdgcn_mfma_f32_16x16x32_bf16(qa, bb, acc1[m][dt], 0, 0, 0);
          acc2[m][dt] = __builtin_amdgcn_mfma_f32_16x16x32_bf16(aa, bb, acc2[m][dt], 0, 0, 0);
        }
      }
      __syncthreads();  // consumers: zero outstanding vmem -> free
      buf = (buf == 2) ? 0 : buf + 1;
    }

    __syncthreads();  // A: producers published sq/sa

    // ---- fold coef, reduce over kh via LDS (reuse sMem), write out ----
    float* red = (float*)sMem;
    if (kh == 1) {
#pragma unroll
      for (int m = 0; m < 3; ++m) {
#pragma unroll
        for (int dt = 0; dt < 4; ++dt) {
          f32x4 fin;
#pragma unroll
          for (int g = 0; g < 4; ++g) {
            const int rr = m * 16 + kgrp * 4 + g;
            const float cfr = sq[rr] > 0.f ? 0.5f * sa[rr] / sq[rr] : 0.f;
            fin[g] = cfr * acc1[m][dt][g] + 0.5f * acc2[m][dt][g];
          }
          *(f32x4*)&red[(((dq * 3 + m) * 4 + dt) * 64 + lane) * 4] = fin;
        }
      }
    }
    __syncthreads();  // B
    if (kh == 0) {
#pragma unroll
      for (int m = 0; m < 3; ++m) {
#pragma unroll
        for (int dt = 0; dt < 4; ++dt) {
          const f32x4 o = *(const f32x4*)&red[(((dq * 3 + m) * 4 + dt) * 64 + lane) * 4];
          const int col = dq * 64 + dt * 16 + lrow;
#pragma unroll
          for (int g = 0; g < 4; ++g) {
            const int rr = m * 16 + kgrp * 4 + g;
            const float cfr = sq[rr] > 0.f ? 0.5f * sa[rr] / sq[rr] : 0.f;
            out[(size_t)(i0 + rr) * DD + col] =
                cfr * acc1[m][dt][g] + 0.5f * acc2[m][dt][g] + o[g];
          }
        }
      }
    }
  } else {
    // ========== PRODUCERS (waves 8..11): score + tiles + B + stats ==========
    const int pid = w - 8;  // 0..3, owns rows 12*pid .. 12*pid+11
    const int c15 = lane & 15, hi4 = lane >> 4;

    // per-(lane,j) fixed row; j in 0..2
    int rowj[3];
    float uc1[3], uc2[3];
    const float* adjp[3];
    int wbyte[3];
#pragma unroll
    for (int j = 0; j < 3; ++j) {
      rowj[j] = 12 * pid + 4 * j + hi4;
      const float ur = u2[i0 + rowj[j]];
      uc1[j] = ur - SHIFT2;
      uc2[j] = fmaf(0.01f, ur, -SHIFT2);
      adjp[j] = adj + (size_t)(i0 + rowj[j]) * NN + c15 * 4;
      wbyte[j] = QOFF + rowj[j] * 128 + ((c15 * 8) ^ ((rowj[j] & 7) << 4));
    }
    const float* vp = v2 + c15 * 4;
    float qs[3] = {0.f, 0.f, 0.f}, as[3] = {0.f, 0.f, 0.f};

    // B staging pointers (fused13 formulas, B at buffer offset 0)
    const int ko = ((lane & 7) ^ (lane >> 3)) << 4;
    const char* pB[8];
    int dB[8];
#pragma unroll
    for (int j = 0; j < 8; ++j) {
      const int ib = pid * 8 + j;
      pB[j] = (const char*)h_poT + (size_t)(ib * 8 + (lane >> 3)) * (NN * 2) + ko;
      dB[j] = ib * 1024;
    }

#define SCORE_WRITE(WB_)                                                      \
    {                                                                         \
      _Pragma("unroll") for (int j = 0; j < 3; ++j) {                         \
        const float af[4] = {av[j].x, av[j].y, av[j].z, av[j].w};             \
        const float vf[4] = {vv.x, vv.y, vv.z, vv.w};                         \
        float qf[4];                                                          \
        _Pragma("unroll") for (int e = 0; e < 4; ++e) {                       \
          const float t1 = uc1[j] + vf[e];                                    \
          const float t2 = fmaf(0.01f, vf[e], uc2[j]);                        \
          float q = exp2_hw(fmaxf(t1, t2));                                   \
          q = (af[e] > 0.f) ? q : 0.f;                                        \
          qs[j] += q; as[j] += af[e]; qf[e] = q;                              \
        }                                                                     \
        *(uint2*)((WB_) + wbyte[j]) =                                         \
            make_uint2(pack_bf2(qf[0], qf[1]), pack_bf2(qf[2], qf[3]));       \
        *(uint2*)((WB_) + wbyte[j] + 6144) =                                  \
            make_uint2(pack_bf2(af[0], af[1]), pack_bf2(af[2], af[3]));       \
      }                                                                       \
    }

    // ---- prologue: tiles(0)+B(0) -> buf0; B(1) -> buf1 ----
    {
      float4 av[3];
#pragma unroll
      for (int j = 0; j < 3; ++j) av[j] = *(const float4*)(adjp[j]);
      float4 vv = *(const float4*)(vp);
#pragma unroll
      for (int j = 0; j < 8; ++j) { gl_lds16(pB[j], sMem + dB[j]); pB[j] += 128; }
      SCORE_WRITE(sMem)                       // buf0 tiles
#pragma unroll
      for (int j = 0; j < 3; ++j) adjp[j] += BK;
      vp += BK;
#pragma unroll
      for (int j = 0; j < 8; ++j) { gl_lds16(pB[j], sMem + BUFSZ2 + dB[j]); pB[j] += 128; }
      asm volatile("s_waitcnt vmcnt(8) lgkmcnt(0)" ::: "memory");  // B(0)+writes done
      __builtin_amdgcn_s_barrier();
    }

    // ---- main loop ----
    int wbi = 1, nbi = 2;  // write tiles(s+1) -> buf wbi; B(s+2) -> buf nbi
    for (int s = 0; s < NSTEPS; ++s) {
      if (s <= NSTEPS - 2) {
        float4 av[3];
#pragma unroll
        for (int j = 0; j < 3; ++j) av[j] = *(const float4*)(adjp[j]);
        float4 vv = *(const float4*)(vp);
        if (s <= NSTEPS - 3) {
          char* nb = sMem + nbi * BUFSZ2;
#pragma unroll
          for (int j = 0; j < 8; ++j) { gl_lds16(pB[j], nb + dB[j]); pB[j] += 128; }
        }
        char* wb = sMem + wbi * BUFSZ2;
        SCORE_WRITE(wb)   // compiler's wait on av retires B(s+1) (in-order)
#pragma unroll
        for (int j = 0; j < 3; ++j) adjp[j] += BK;
        vp += BK;
      }
      asm volatile("s_waitcnt lgkmcnt(0)" ::: "memory");
      __builtin_amdgcn_s_barrier();
      wbi = (wbi == 2) ? 0 : wbi + 1;
      nbi = (nbi == 2) ? 0 : nbi + 1;
    }

    // ---- stats: reduce qs/as over the 16-lane k-groups, publish sq/sa ----
#pragma unroll
    for (int j = 0; j < 3; ++j) {
#pragma unroll
      for (int m = 1; m <= 8; m <<= 1) {
        qs[j] += __shfl_xor(qs[j], m, 64);
        as[j] += __shfl_xor(as[j], m, 64);
      }
    }
    if (c15 == 0) {
#pragma unroll
      for (int j = 0; j < 3; ++j) {
        sq[rowj[j]] = qs[j];
        sa[rowj[j]] = as[j];
      }
    }
    __syncthreads();  // A
    __syncthreads();  // B
#undef SCORE_WRITE
  }
}

// ---------------- fallback (small ws): round-2 proven kernel ----------------
__global__ __launch_bounds__(256) void fused_fb(
    const float* __restrict__ adj, const float* __restrict__ u,
    const float* __restrict__ v, const float* __restrict__ hpo,
    float* __restrict__ out) {
#define BMF 32
#define LDA 40
  __shared__ unsigned short qlds[BMF][LDA];
  __shared__ unsigned short alds[BMF][LDA];
  __shared__ unsigned short btf[DD][LDA];
  __shared__ float denom_s[BMF], deg_s[BMF], coef_s[BMF];

  const int t = threadIdx.x;
  const int wave = t >> 6, lane = t & 63;
  const int i0 = blockIdx.x * BMF;
  const int sr = t >> 3;
  const int sc = (t & 7) * 4;
  const float u_r = u[i0 + sr];
  const int d0 = wave * 64;
  const int lrow = lane & 15;
  const int kgrp = lane >> 4;

  f32x4 acc1[2][4] = {};
  f32x4 acc2[2][4] = {};
  float qsum = 0.f, asum = 0.f;

  const float* arow = adj + (size_t)(i0 + sr) * NN + sc;
  float4 a_cur = *(const float4*)(arow);

  constexpr int NSTEP = NN / 32;
  for (int jt = 0; jt < NSTEP; ++jt) {
    const int j = jt * 32;
    float4 a_nxt;
    const bool has_next = (jt + 1 < NSTEP);
    if (has_next) a_nxt = *(const float4*)(arow + j + 32);
    const float4 vv = *(const float4*)(v + j + sc);
    unsigned short qb[4], ab[4];
    {
      const float aa4[4] = {a_cur.x, a_cur.y, a_cur.z, a_cur.w};
      const float vvv[4] = {vv.x, vv.y, vv.z, vv.w};
#pragma unroll
      for (int k = 0; k < 4; ++k) {
        const float a = aa4[k];
        const float s = u_r + vvv[k];
        const float x = fmaxf(s, 0.01f * s);
        const float q = (a > 0.f) ? exp2_hw(x - SHIFT2) : 0.f;
        qsum += q;
        asum += a;
        qb[k] = f2bf(q);
        ab[k] = f2bf(a);
      }
    }
    *(uint2*)&qlds[sr][sc] = make_uint2((unsigned)qb[0] | ((unsigned)qb[1] << 16),
                                        (unsigned)qb[2] | ((unsigned)qb[3] << 16));
    *(uint2*)&alds[sr][sc] = make_uint2((unsigned)ab[0] | ((unsigned)ab[1] << 16),
                                        (unsigned)ab[2] | ((unsigned)ab[3] << 16));
    {
      const int br = t >> 3;
      const float* src = hpo + (size_t)(j + br) * DD;
#pragma unroll
      for (int cc = 0; cc < 8; ++cc) {
        const int c = (t & 7) * 4 + cc * 32;
        const float4 hv = *(const float4*)(src + c);
        btf[c + 0][br] = f2bf(hv.x);
        btf[c + 1][br] = f2bf(hv.y);
        btf[c + 2][br] = f2bf(hv.z);
        btf[c + 3][br] = f2bf(hv.w);
      }
    }
    __syncthreads();

    const s16x8 qa0 = *(const s16x8*)&qlds[lrow][kgrp * 8];
    const s16x8 qa1 = *(const s16x8*)&qlds[16 + lrow][kgrp * 8];
    const s16x8 ad0 = *(const s16x8*)&alds[lrow][kgrp * 8];
    const s16x8 ad1 = *(const s16x8*)&alds[16 + lrow][kgrp * 8];
#pragma unroll
    for (int dt = 0; dt < 4; ++dt) {
      const s16x8 b = *(const s16x8*)&btf[d0 + dt * 16 + lrow][kgrp * 8];
      acc1[0][dt] = __builtin_amdgcn_mfma_f32_16x16x32_bf16(qa0, b, acc1[0][dt], 0, 0, 0);
      acc1[1][dt] = __builtin_amdgcn_mfma_f32_16x16x32_bf16(qa1, b, acc1[1][dt], 0, 0, 0);
      acc2[0][dt] = __builtin_amdgcn_mfma_f32_16x16x32_bf16(ad0, b, acc2[0][dt], 0, 0, 0);
      acc2[1][dt] = __builtin_amdgcn_mfma_f32_16x16x32_bf16(ad1, b, acc2[1][dt], 0, 0, 0);
    }
    __syncthreads();
    if (has_next) a_cur = a_nxt;
  }
#pragma unroll
  for (int m = 1; m <= 4; m <<= 1) {
    qsum += __shfl_xor(qsum, m, 64);
    asum += __shfl_xor(asum, m, 64);
  }
  if ((t & 7) == 0) { denom_s[sr] = qsum; deg_s[sr] = asum; }
  __syncthreads();
  if (t < BMF) {
    const float dn = denom_s[t];
    coef_s[t] = dn > 0.f ? 0.5f * deg_s[t] / dn : 0.f;
  }
  __syncthreads();
#pragma unroll
  for (int f = 0; f < 2; ++f) {
#pragma unroll
    for (int dt = 0; dt < 4; ++dt) {
      const int col = d0 + dt * 16 + lrow;
#pragma unroll
      for (int g = 0; g < 4; ++g) {
        const int r = f * 16 + kgrp * 4 + g;
        out[(size_t)(i0 + r) * DD + col] =
            coef_s[r] * acc1[f][dt][g] + 0.5f * acc2[f][dt][g];
      }
    }
  }
}

extern "C" void kernel_launch(void* const* d_in, const int* in_sizes, int n_in,
                              void* d_out, int out_size, void* d_ws, size_t ws_size,
                              hipStream_t stream) {
  const float* h_eu = (const float*)d_in[0];
  const float* h_po = (const float*)d_in[1];
  const float* h_lo = (const float*)d_in[2];
  const float* adj  = (const float*)d_in[3];
  const float* a1   = (const float*)d_in[4];
  const float* a2   = (const float*)d_in[5];
  const float* a3   = (const float*)d_in[6];
  float* out = (float*)d_out;

  // ws layout: u[N] | v[N] | h_poT[D*N] bf16 = 6,389,760 B
  const size_t need_full = (size_t)2 * NN * 4 + (size_t)NN * DD * 2;
  float* u = (float*)d_ws;
  float* v = u + NN;
  unsigned short* h_poT = (unsigned short*)(v + NN);
  const bool big_ws = ws_size >= need_full;

  prep_uv<<<NN / 64, 256, 0, stream>>>(h_eu, h_po, h_lo, a1, a2, a3, u, v);
  if (big_ws) {
    prep_T<<<NN / 64, 256, 0, stream>>>(h_po, h_poT);
    fused16<<<NN / BM, 768, 0, stream>>>(adj, u, v, h_poT, out);
  } else {
    fused_fb<<<NN / 32, 256, 0, stream>>>(adj, u, v, h_po, out);
  }
}

// Round 17
// 309.303 us; speedup vs baseline: 2.1577x; 1.0875x over previous
//
#include <hip/hip_runtime.h>
#include <hip/hip_bf16.h>

// N=12288, D=256. Single pass:
//   e=lrelu(u_i+v_j); q=exp2(e*log2e-SHIFT2) masked adj>0 (const shift, scale-free)
//   out_i = coef_i*(q_i@h_po) + 0.5*(adj_i@h_po),  coef_i=0.5*deg_i/denom_i
// fused17 = fused16 (scorer-producer; verified correct) + producer REGISTER
// DOUBLE-BUFFER for adj/v (the one flaw r16 exposed: depth-0 adj loads put
// ~900cy HBM latency on the producer critical path every slot).
//   Producer slot k: issue B(k+2) gl_lds -> buf(k+2)%3; load av(k+2) into the
//   free reg slot; score av(k+1) (loaded a full slot ago -> latency hidden);
//   ds_write tiles(k+1); lgkmcnt(0); s_barrier. Compiler's auto-wait on
//   av(k+1) retires B(k+1) (in-order, m135) -> residency guaranteed.
//   Consumers byte-identical to fused16: pure GEMM, 10 ds_read_b128/step,
//   B read once per (dq,kh), free __syncthreads.

#define NN 12288
#define DD 256
#define BM 48
#define BK 64
#define NSTEPS (NN / BK)   // 192
#define QOFF 32768
#define AOFF 38912         // QOFF + 6144
#define BUFSZ2 45056       // B 32768 + q 6144 + a 6144
#define LOG2E 1.44269504f
#define SHIFT2 36.067376f  // 25*log2e

typedef __attribute__((ext_vector_type(8))) short s16x8;
typedef __attribute__((ext_vector_type(4))) float f32x4;

__device__ __forceinline__ unsigned short f2bf(float f) {
  unsigned u = __builtin_bit_cast(unsigned, f);
  u += 0x7FFFu + ((u >> 16) & 1u);
  return (unsigned short)(u >> 16);
}
__device__ __forceinline__ unsigned pack_bf2(float a, float b) {
  unsigned short lo = __builtin_bit_cast(unsigned short, __float2bfloat16(a));
  unsigned short hi = __builtin_bit_cast(unsigned short, __float2bfloat16(b));
  return (unsigned)lo | ((unsigned)hi << 16);
}
__device__ __forceinline__ float exp2_hw(float x) {
  float r;
  asm("v_exp_f32 %0, %1" : "=v"(r) : "v"(x));
  return r;
}
__device__ __forceinline__ void gl_lds16(const void* g, void* l) {
  __builtin_amdgcn_global_load_lds(
      (const __attribute__((address_space(1))) void*)g,
      (__attribute__((address_space(3))) void*)l, 16, 0, 0);
}

// ---------------- prep: u2, v2 (pre-scaled by log2e) ----------------
__global__ __launch_bounds__(256) void prep_uv(
    const float* __restrict__ h_eu, const float* __restrict__ h_po,
    const float* __restrict__ h_lo, const float* __restrict__ a1,
    const float* __restrict__ a2, const float* __restrict__ a3,
    float* __restrict__ u, float* __restrict__ v) {
  const int t = threadIdx.x;
  const int wave = t >> 6, lane = t & 63;
  const int r0 = blockIdx.x * 64;
  for (int rr = 0; rr < 16; ++rr) {
    const int row = r0 + wave * 16 + rr;
    const float* pe = h_eu + (size_t)row * DD;
    const float* pl = h_lo + (size_t)row * DD;
    const float* pp = h_po + (size_t)row * DD;
    float su = 0.f, sv = 0.f;
#pragma unroll
    for (int c = 0; c < 4; ++c) {
      const int d = lane + c * 64;
      su = fmaf(pe[d], a1[d], su);
      su = fmaf(pl[d], a3[d], su);
      sv = fmaf(pp[d], a2[d], sv);
    }
#pragma unroll
    for (int m = 32; m; m >>= 1) {
      su += __shfl_xor(su, m, 64);
      sv += __shfl_xor(sv, m, 64);
    }
    if (lane == 0) { u[row] = su * LOG2E; v[row] = sv * LOG2E; }
  }
}

// ---------------- prep: h_poT (bf16, [D][N]) ----------------
__global__ __launch_bounds__(256) void prep_T(
    const float* __restrict__ hpo, unsigned short* __restrict__ h_poT) {
  const int t = threadIdx.x;
  const int r0 = blockIdx.x * 64;
  unsigned short* dst = h_poT + (size_t)t * NN + r0;
#pragma unroll
  for (int c = 0; c < 16; ++c) {
    unsigned short x0 = f2bf(hpo[(size_t)(r0 + c * 4 + 0) * DD + t]);
    unsigned short x1 = f2bf(hpo[(size_t)(r0 + c * 4 + 1) * DD + t]);
    unsigned short x2 = f2bf(hpo[(size_t)(r0 + c * 4 + 2) * DD + t]);
    unsigned short x3 = f2bf(hpo[(size_t)(r0 + c * 4 + 3) * DD + t]);
    ((uint2*)dst)[c] = make_uint2((unsigned)x0 | ((unsigned)x1 << 16),
                                  (unsigned)x2 | ((unsigned)x3 << 16));
  }
}

// ---------------- fused17 ----------------
__global__ __launch_bounds__(768, 3) void fused17(
    const float* __restrict__ adj, const float* __restrict__ u2,
    const float* __restrict__ v2, const unsigned short* __restrict__ h_poT,
    float* __restrict__ out) {
  __shared__ __align__(16) char sMem[3 * BUFSZ2];  // 135,168 B
  __shared__ float sq[BM], sa[BM];

  const int t = threadIdx.x;
  const int w = t >> 6, lane = t & 63;
  const int lrow = lane & 15, kgrp = lane >> 4;
  const int i0 = blockIdx.x * BM;

  if (w < 8) {
    // ========== CONSUMERS (waves 0..7): pure GEMM, 4 dq x 2 kh, m_rep=3 =====
    const int dq = w >> 1;           // 0..3 D-quarter (64 cols)
    const int kh = w & 1;            // 0..1 k-slice (32 of 64)
    const int xr = (lrow & 7) << 4;
    const int kSel = (kh * 64 + kgrp * 16) ^ xr;
    const int bBase0 = (dq * 64 + lrow) * 128 + kSel;   // + dt*2048
    const int qBase0 = QOFF + lrow * 128 + kSel;        // + m*2048
    const int aBase0 = AOFF + lrow * 128 + kSel;

    f32x4 acc1[3][4] = {};  // q   @ B   (m x dt)
    f32x4 acc2[3][4] = {};  // adj @ B

    __syncthreads();  // prologue: producers staged buf0 tiles + B

    int buf = 0;
    for (int s = 0; s < NSTEPS; ++s) {
      const char* bufp = sMem + buf * BUFSZ2;
      uint4 b[4];
#pragma unroll
      for (int dt = 0; dt < 4; ++dt)
        b[dt] = *(const uint4*)(bufp + bBase0 + dt * 2048);
#pragma unroll
      for (int m = 0; m < 3; ++m) {
        const s16x8 qa = *(const s16x8*)(bufp + qBase0 + m * 2048);
        const s16x8 aa = *(const s16x8*)(bufp + aBase0 + m * 2048);
#pragma unroll
        for (int dt = 0; dt < 4; ++dt) {
          const s16x8 bb = __builtin_bit_cast(s16x8, b[dt]);
          acc1[m][dt] = __builtin_amdgcn_mfma_f32_16x16x32_bf16(qa, bb, acc1[m][dt], 0, 0, 0);
          acc2[m][dt] = __builtin_amdgcn_mfma_f32_16x16x32_bf16(aa, bb, acc2[m][dt], 0, 0, 0);
        }
      }
      __syncthreads();  // consumers: zero outstanding vmem -> free
      buf = (buf == 2) ? 0 : buf + 1;
    }

    __syncthreads();  // A: producers published sq/sa

    // ---- fold coef, reduce over kh via LDS (reuse sMem), write out ----
    float* red = (float*)sMem;
    if (kh == 1) {
#pragma unroll
      for (int m = 0; m < 3; ++m) {
#pragma unroll
        for (int dt = 0; dt < 4; ++dt) {
          f32x4 fin;
#pragma unroll
          for (int g = 0; g < 4; ++g) {
            const int rr = m * 16 + kgrp * 4 + g;
            const float cfr = sq[rr] > 0.f ? 0.5f * sa[rr] / sq[rr] : 0.f;
            fin[g] = cfr * acc1[m][dt][g] + 0.5f * acc2[m][dt][g];
          }
          *(f32x4*)&red[(((dq * 3 + m) * 4 + dt) * 64 + lane) * 4] = fin;
        }
      }
    }
    __syncthreads();  // B
    if (kh == 0) {
#pragma unroll
      for (int m = 0; m < 3; ++m) {
#pragma unroll
        for (int dt = 0; dt < 4; ++dt) {
          const f32x4 o = *(const f32x4*)&red[(((dq * 3 + m) * 4 + dt) * 64 + lane) * 4];
          const int col = dq * 64 + dt * 16 + lrow;
#pragma unroll
          for (int g = 0; g < 4; ++g) {
            const int rr = m * 16 + kgrp * 4 + g;
            const float cfr = sq[rr] > 0.f ? 0.5f * sa[rr] / sq[rr] : 0.f;
            out[(size_t)(i0 + rr) * DD + col] =
                cfr * acc1[m][dt][g] + 0.5f * acc2[m][dt][g] + o[g];
          }
        }
      }
    }
  } else {
    // ========== PRODUCERS (waves 8..11): score + tiles + B + stats ==========
    const int pid = w - 8;  // 0..3, owns rows 12*pid .. 12*pid+11
    const int c15 = lane & 15, hi4 = lane >> 4;

    int rowj[3];
    float uc1[3], uc2[3];
    const float* adjp[3];
    int wbyte[3];
#pragma unroll
    for (int j = 0; j < 3; ++j) {
      rowj[j] = 12 * pid + 4 * j + hi4;
      const float ur = u2[i0 + rowj[j]];
      uc1[j] = ur - SHIFT2;
      uc2[j] = fmaf(0.01f, ur, -SHIFT2);
      adjp[j] = adj + (size_t)(i0 + rowj[j]) * NN + c15 * 4;
      wbyte[j] = QOFF + rowj[j] * 128 + ((c15 * 8) ^ ((rowj[j] & 7) << 4));
    }
    const float* vp = v2 + c15 * 4;
    float qs[3] = {0.f, 0.f, 0.f}, as[3] = {0.f, 0.f, 0.f};

    // B staging pointers (B at buffer offset 0)
    const int ko = ((lane & 7) ^ (lane >> 3)) << 4;
    const char* pB[8];
    int dB[8];
#pragma unroll
    for (int j = 0; j < 8; ++j) {
      const int ib = pid * 8 + j;
      pB[j] = (const char*)h_poT + (size_t)(ib * 8 + (lane >> 3)) * (NN * 2) + ko;
      dB[j] = ib * 1024;
    }

    // register double-buffer for adj/v (static slots; pointers self-advance)
    float4 avA[3], avB[3], vvA, vvB;

#define LOAD_AV(AV_, VV_)                                                     \
    {                                                                         \
      _Pragma("unroll") for (int j = 0; j < 3; ++j) {                         \
        AV_[j] = *(const float4*)(adjp[j]);                                   \
        adjp[j] += BK;                                                        \
      }                                                                       \
      VV_ = *(const float4*)(vp); vp += BK;                                   \
    }

#define ISSUE_B(NB_)                                                          \
    {                                                                         \
      char* nb_ = sMem + (NB_)*BUFSZ2;                                        \
      _Pragma("unroll") for (int j = 0; j < 8; ++j) {                         \
        gl_lds16(pB[j], nb_ + dB[j]);                                         \
        pB[j] += 128;                                                         \
      }                                                                       \
    }

#define SCORE_WRITE(AV_, VV_, WB_)                                            \
    {                                                                         \
      char* wb_ = sMem + (WB_)*BUFSZ2;                                        \
      _Pragma("unroll") for (int j = 0; j < 3; ++j) {                         \
        const float af[4] = {AV_[j].x, AV_[j].y, AV_[j].z, AV_[j].w};         \
        const float vf[4] = {VV_.x, VV_.y, VV_.z, VV_.w};                     \
        float qf[4];                                                          \
        _Pragma("unroll") for (int e = 0; e < 4; ++e) {                       \
          const float t1 = uc1[j] + vf[e];                                    \
          const float t2 = fmaf(0.01f, vf[e], uc2[j]);                        \
          float q = exp2_hw(fmaxf(t1, t2));                                   \
          q = (af[e] > 0.f) ? q : 0.f;                                        \
          qs[j] += q; as[j] += af[e]; qf[e] = q;                              \
        }                                                                     \
        *(uint2*)(wb_ + wbyte[j]) =                                           \
            make_uint2(pack_bf2(qf[0], qf[1]), pack_bf2(qf[2], qf[3]));       \
        *(uint2*)(wb_ + wbyte[j] + 6144) =                                    \
            make_uint2(pack_bf2(af[0], af[1]), pack_bf2(af[2], af[3]));       \
      }                                                                       \
    }

#define PSYNC { asm volatile("s_waitcnt lgkmcnt(0)" ::: "memory"); \
                __builtin_amdgcn_s_barrier(); }

    // ---- prologue: B(0)->buf0, av(0); B(1)->buf1, av(1); tiles(0) ----
    ISSUE_B(0)
    LOAD_AV(avA, vvA)          // av(0)
    ISSUE_B(1)
    LOAD_AV(avB, vvB)          // av(1)
    SCORE_WRITE(avA, vvA, 0)   // tiles(0); auto-wait retires B(0)+av(0)
    PSYNC                       // barrier #1 (matches consumer prologue)

    // ---- main: slots 0..189 (95 x 2), each writes tiles(k+1) ----
    int nbi = 2, wbi = 1;
    for (int it = 0; it < 95; ++it) {
      // even slot k=2it: load av(k+2)->A, score av(k+1)=B
      ISSUE_B(nbi)
      LOAD_AV(avA, vvA)
      SCORE_WRITE(avB, vvB, wbi)
      PSYNC
      nbi = (nbi == 2) ? 0 : nbi + 1;
      wbi = (wbi == 2) ? 0 : wbi + 1;
      // odd slot k=2it+1: load av(k+2)->B, score av(k+1)=A
      ISSUE_B(nbi)
      LOAD_AV(avB, vvB)
      SCORE_WRITE(avA, vvA, wbi)
      PSYNC
      nbi = (nbi == 2) ? 0 : nbi + 1;
      wbi = (wbi == 2) ? 0 : wbi + 1;
    }
    // slot 190: score av(191) (odd index -> slot B), no loads
    SCORE_WRITE(avB, vvB, wbi)
    PSYNC
    // slot 191: barrier only
    __builtin_amdgcn_s_barrier();

#undef LOAD_AV
#undef ISSUE_B
#undef SCORE_WRITE
#undef PSYNC

    // ---- stats: reduce qs/as over the 16-lane k-groups, publish sq/sa ----
#pragma unroll
    for (int j = 0; j < 3; ++j) {
#pragma unroll
      for (int m = 1; m <= 8; m <<= 1) {
        qs[j] += __shfl_xor(qs[j], m, 64);
        as[j] += __shfl_xor(as[j], m, 64);
      }
    }
    if (c15 == 0) {
#pragma unroll
      for (int j = 0; j < 3; ++j) {
        sq[rowj[j]] = qs[j];
        sa[rowj[j]] = as[j];
      }
    }
    __syncthreads();  // A
    __syncthreads();  // B
  }
}

// ---------------- fallback (small ws): round-2 proven kernel ----------------
__global__ __launch_bounds__(256) void fused_fb(
    const float* __restrict__ adj, const float* __restrict__ u,
    const float* __restrict__ v, const float* __restrict__ hpo,
    float* __restrict__ out) {
#define BMF 32
#define LDA 40
  __shared__ unsigned short qlds[BMF][LDA];
  __shared__ unsigned short alds[BMF][LDA];
  __shared__ unsigned short btf[DD][LDA];
  __shared__ float denom_s[BMF], deg_s[BMF], coef_s[BMF];

  const int t = threadIdx.x;
  const int wave = t >> 6, lane = t & 63;
  const int i0 = blockIdx.x * BMF;
  const int sr = t >> 3;
  const int sc = (t & 7) * 4;
  const float u_r = u[i0 + sr];
  const int d0 = wave * 64;
  const int lrow = lane & 15;
  const int kgrp = lane >> 4;

  f32x4 acc1[2][4] = {};
  f32x4 acc2[2][4] = {};
  float qsum = 0.f, asum = 0.f;

  const float* arow = adj + (size_t)(i0 + sr) * NN + sc;
  float4 a_cur = *(const float4*)(arow);

  constexpr int NSTEP = NN / 32;
  for (int jt = 0; jt < NSTEP; ++jt) {
    const int j = jt * 32;
    float4 a_nxt;
    const bool has_next = (jt + 1 < NSTEP);
    if (has_next) a_nxt = *(const float4*)(arow + j + 32);
    const float4 vv = *(const float4*)(v + j + sc);
    unsigned short qb[4], ab[4];
    {
      const float aa4[4] = {a_cur.x, a_cur.y, a_cur.z, a_cur.w};
      const float vvv[4] = {vv.x, vv.y, vv.z, vv.w};
#pragma unroll
      for (int k = 0; k < 4; ++k) {
        const float a = aa4[k];
        const float s = u_r + vvv[k];
        const float x = fmaxf(s, 0.01f * s);
        const float q = (a > 0.f) ? exp2_hw(x - SHIFT2) : 0.f;
        qsum += q;
        asum += a;
        qb[k] = f2bf(q);
        ab[k] = f2bf(a);
      }
    }
    *(uint2*)&qlds[sr][sc] = make_uint2((unsigned)qb[0] | ((unsigned)qb[1] << 16),
                                        (unsigned)qb[2] | ((unsigned)qb[3] << 16));
    *(uint2*)&alds[sr][sc] = make_uint2((unsigned)ab[0] | ((unsigned)ab[1] << 16),
                                        (unsigned)ab[2] | ((unsigned)ab[3] << 16));
    {
      const int br = t >> 3;
      const float* src = hpo + (size_t)(j + br) * DD;
#pragma unroll
      for (int cc = 0; cc < 8; ++cc) {
        const int c = (t & 7) * 4 + cc * 32;
        const float4 hv = *(const float4*)(src + c);
        btf[c + 0][br] = f2bf(hv.x);
        btf[c + 1][br] = f2bf(hv.y);
        btf[c + 2][br] = f2bf(hv.z);
        btf[c + 3][br] = f2bf(hv.w);
      }
    }
    __syncthreads();

    const s16x8 qa0 = *(const s16x8*)&qlds[lrow][kgrp * 8];
    const s16x8 qa1 = *(const s16x8*)&qlds[16 + lrow][kgrp * 8];
    const s16x8 ad0 = *(const s16x8*)&alds[lrow][kgrp * 8];
    const s16x8 ad1 = *(const s16x8*)&alds[16 + lrow][kgrp * 8];
#pragma unroll
    for (int dt = 0; dt < 4; ++dt) {
      const s16x8 b = *(const s16x8*)&btf[d0 + dt * 16 + lrow][kgrp * 8];
      acc1[0][dt] = __builtin_amdgcn_mfma_f32_16x16x32_bf16(qa0, b, acc1[0][dt], 0, 0, 0);
      acc1[1][dt] = __builtin_amdgcn_mfma_f32_16x16x32_bf16(qa1, b, acc1[1][dt], 0, 0, 0);
      acc2[0][dt] = __builtin_amdgcn_mfma_f32_16x16x32_bf16(ad0, b, acc2[0][dt], 0, 0, 0);
      acc2[1][dt] = __builtin_amdgcn_mfma_f32_16x16x32_bf16(ad1, b, acc2[1][dt], 0, 0, 0);
    }
    __syncthreads();
    if (has_next) a_cur = a_nxt;
  }
#pragma unroll
  for (int m = 1; m <= 4; m <<= 1) {
    qsum += __shfl_xor(qsum, m, 64);
    asum += __shfl_xor(asum, m, 64);
  }
  if ((t & 7) == 0) { denom_s[sr] = qsum; deg_s[sr] = asum; }
  __syncthreads();
  if (t < BMF) {
    const float dn = denom_s[t];
    coef_s[t] = dn > 0.f ? 0.5f * deg_s[t] / dn : 0.f;
  }
  __syncthreads();
#pragma unroll
  for (int f = 0; f < 2; ++f) {
#pragma unroll
    for (int dt = 0; dt < 4; ++dt) {
      const int col = d0 + dt * 16 + lrow;
#pragma unroll
      for (int g = 0; g < 4; ++g) {
        const int r = f * 16 + kgrp * 4 + g;
        out[(size_t)(i0 + r) * DD + col] =
            coef_s[r] * acc1[f][dt][g] + 0.5f * acc2[f][dt][g];
      }
    }
  }
}

extern "C" void kernel_launch(void* const* d_in, const int* in_sizes, int n_in,
                              void* d_out, int out_size, void* d_ws, size_t ws_size,
                              hipStream_t stream) {
  const float* h_eu = (const float*)d_in[0];
  const float* h_po = (const float*)d_in[1];
  const float* h_lo = (const float*)d_in[2];
  const float* adj  = (const float*)d_in[3];
  const float* a1   = (const float*)d_in[4];
  const float* a2   = (const float*)d_in[5];
  const float* a3   = (const float*)d_in[6];
  float* out = (float*)d_out;

  // ws layout: u[N] | v[N] | h_poT[D*N] bf16 = 6,389,760 B
  const size_t need_full = (size_t)2 * NN * 4 + (size_t)NN * DD * 2;
  float* u = (float*)d_ws;
  float* v = u + NN;
  unsigned short* h_poT = (unsigned short*)(v + NN);
  const bool big_ws = ws_size >= need_full;

  prep_uv<<<NN / 64, 256, 0, stream>>>(h_eu, h_po, h_lo, a1, a2, a3, u, v);
  if (big_ws) {
    prep_T<<<NN / 64, 256, 0, stream>>>(h_po, h_poT);
    fused17<<<NN / BM, 768, 0, stream>>>(adj, u, v, h_poT, out);
  } else {
    fused_fb<<<NN / 32, 256, 0, stream>>>(adj, u, v, h_po, out);
  }
}

// Round 18
// 249.739 us; speedup vs baseline: 2.6724x; 1.2385x over previous
//
#include <hip/hip_runtime.h>
#include <hip/hip_bf16.h>

// N=12288, D=256. Single pass:
//   e=lrelu(u_i+v_j); q=exp2(e*log2e-SHIFT2) masked adj>0 (const shift, scale-free)
//   out_i = coef_i*(q_i@h_po) + 0.5*(adj_i@h_po),  coef_i=0.5*deg_i/denom_i
// fused18 = fused13 (best, 253us) with ROLE-SPLIT producers + deeper adj pipe:
//   - 12 consumer waves: BYTE-IDENTICAL to fused13 (score inline, 12 ds_read
//     b128/step, free __syncthreads)
//   - 2 adj-producer waves: 7 ops/step (6 adj gl_lds16 + 1 v gl_lds4),
//     staging step s+3 into a 4-DEEP adj buffer; vmcnt(14) = 2 batches in
//     flight across the barrier (fused13 had 1 -> HBM at 25%; this doubles
//     the adj in-flight window, the measured binding constraint)
//   - 2 B-producer waves: 16 ops/step, step s+2, 3-deep B buffer, vmcnt(16)
//   - per-wave op counts uniform WITHIN each role -> counted waits exact
//     (m135 in-order); tail waits per role: adj 14->7->0, B 16->0
//   - LDS: 4x12544 (adj+v) + 3x32768 (B) = 148,864 B

#define NN 12288
#define DD 256
#define BM 48
#define BK 64
#define NSTEPS (NN / BK)   // 192
#define ABUFSZ 12544       // adj 12288 + v 256
#define AVOFF 12288        // v offset within adj buffer
#define BBUFSZ 32768
#define LOG2E 1.44269504f
#define SHIFT2 36.067376f  // 25*log2e

typedef __attribute__((ext_vector_type(8))) short s16x8;
typedef __attribute__((ext_vector_type(4))) float f32x4;

__device__ __forceinline__ unsigned short f2bf(float f) {
  unsigned u = __builtin_bit_cast(unsigned, f);
  u += 0x7FFFu + ((u >> 16) & 1u);
  return (unsigned short)(u >> 16);
}
__device__ __forceinline__ unsigned pack_bf2(float a, float b) {
  unsigned short lo = __builtin_bit_cast(unsigned short, __float2bfloat16(a));
  unsigned short hi = __builtin_bit_cast(unsigned short, __float2bfloat16(b));
  return (unsigned)lo | ((unsigned)hi << 16);
}
__device__ __forceinline__ float exp2_hw(float x) {
  float r;
  asm("v_exp_f32 %0, %1" : "=v"(r) : "v"(x));
  return r;
}
__device__ __forceinline__ void gl_lds16(const void* g, void* l) {
  __builtin_amdgcn_global_load_lds(
      (const __attribute__((address_space(1))) void*)g,
      (__attribute__((address_space(3))) void*)l, 16, 0, 0);
}
__device__ __forceinline__ void gl_lds4(const void* g, void* l) {
  __builtin_amdgcn_global_load_lds(
      (const __attribute__((address_space(1))) void*)g,
      (__attribute__((address_space(3))) void*)l, 4, 0, 0);
}

// ---------------- prep: u2, v2 (pre-scaled by log2e) ----------------
__global__ __launch_bounds__(256) void prep_uv(
    const float* __restrict__ h_eu, const float* __restrict__ h_po,
    const float* __restrict__ h_lo, const float* __restrict__ a1,
    const float* __restrict__ a2, const float* __restrict__ a3,
    float* __restrict__ u, float* __restrict__ v) {
  const int t = threadIdx.x;
  const int wave = t >> 6, lane = t & 63;
  const int r0 = blockIdx.x * 64;
  for (int rr = 0; rr < 16; ++rr) {
    const int row = r0 + wave * 16 + rr;
    const float* pe = h_eu + (size_t)row * DD;
    const float* pl = h_lo + (size_t)row * DD;
    const float* pp = h_po + (size_t)row * DD;
    float su = 0.f, sv = 0.f;
#pragma unroll
    for (int c = 0; c < 4; ++c) {
      const int d = lane + c * 64;
      su = fmaf(pe[d], a1[d], su);
      su = fmaf(pl[d], a3[d], su);
      sv = fmaf(pp[d], a2[d], sv);
    }
#pragma unroll
    for (int m = 32; m; m >>= 1) {
      su += __shfl_xor(su, m, 64);
      sv += __shfl_xor(sv, m, 64);
    }
    if (lane == 0) { u[row] = su * LOG2E; v[row] = sv * LOG2E; }
  }
}

// ---------------- prep: h_poT (bf16, [D][N]) ----------------
__global__ __launch_bounds__(256) void prep_T(
    const float* __restrict__ hpo, unsigned short* __restrict__ h_poT) {
  const int t = threadIdx.x;
  const int r0 = blockIdx.x * 64;
  unsigned short* dst = h_poT + (size_t)t * NN + r0;
#pragma unroll
  for (int c = 0; c < 16; ++c) {
    unsigned short x0 = f2bf(hpo[(size_t)(r0 + c * 4 + 0) * DD + t]);
    unsigned short x1 = f2bf(hpo[(size_t)(r0 + c * 4 + 1) * DD + t]);
    unsigned short x2 = f2bf(hpo[(size_t)(r0 + c * 4 + 2) * DD + t]);
    unsigned short x3 = f2bf(hpo[(size_t)(r0 + c * 4 + 3) * DD + t]);
    ((uint2*)dst)[c] = make_uint2((unsigned)x0 | ((unsigned)x1 << 16),
                                  (unsigned)x2 | ((unsigned)x3 << 16));
  }
}

// ---------------- fused18 ----------------
__global__ __launch_bounds__(1024) void fused18(
    const float* __restrict__ adj, const float* __restrict__ u2,
    const float* __restrict__ v2, const unsigned short* __restrict__ h_poT,
    float* __restrict__ out) {
  __shared__ __align__(16) char sAdjM[4 * ABUFSZ];  // 50,176 B (adj+v, 4-deep)
  __shared__ __align__(16) char sBM[3 * BBUFSZ];    // 98,304 B (B, 3-deep)
  __shared__ float sq[2][3][16], sa[2][3][16];

  const int t = threadIdx.x;
  const int w = t >> 6, lane = t & 63;
  const int lrow = lane & 15, kgrp = lane >> 4;
  const int i0 = blockIdx.x * BM;

  if (w < 12) {
    // ============ CONSUMERS (waves 0..11): fused13's branch ============
    const int rg = w >> 2;           // 0..2 row-group
    const int dh = (w >> 1) & 1;     // 0..1 D-half
    const int kh = w & 1;            // 0..1 k-slice
    const int row = i0 + rg * 16 + lrow;
    const float u_r = u2[row];
    const float uc1 = u_r - SHIFT2;
    const float uc2 = fmaf(0.01f, u_r, -SHIFT2);
    const int xr = (lrow & 7) << 4;

    const int aOff = (rg * 16 + lrow) * 256;
    const int kA0 = (kh * 128 + kgrp * 32) ^ xr;
    const int kA1 = (kh * 128 + kgrp * 32 + 16) ^ xr;
    const int bOff = (dh * 128 + lrow) * 128 + ((kh * 64 + kgrp * 16) ^ xr);
    const int vOff = AVOFF + (kh * 32 + kgrp * 8) * 4;

    f32x4 acc1[8] = {};  // q   @ B
    f32x4 acc2[8] = {};  // adj @ B
    float qsum = 0.f, asum = 0.f;

    __syncthreads();  // prologue: producers staged their pipelines

    int ab = 0, bb = 0;
    for (int s = 0; s < NSTEPS; ++s) {
      const char* abufp = sAdjM + ab * ABUFSZ;
      const char* bbufp = sBM + bb * BBUFSZ;
      const f32x4 Vv0 = *(const f32x4*)(abufp + vOff);
      const f32x4 Vv1 = *(const f32x4*)(abufp + vOff + 16);
      const char* abp = abufp + aOff;
      const f32x4 A0 = *(const f32x4*)(abp + kA0);
      const f32x4 A1 = *(const f32x4*)(abp + kA1);
      const float af[8] = {A0[0], A0[1], A0[2], A0[3],
                           A1[0], A1[1], A1[2], A1[3]};
      const float vf[8] = {Vv0[0], Vv0[1], Vv0[2], Vv0[3],
                           Vv1[0], Vv1[1], Vv1[2], Vv1[3]};
      float qv[8];
#pragma unroll
      for (int e = 0; e < 8; ++e) {
        const float t1 = uc1 + vf[e];
        const float t2 = fmaf(0.01f, vf[e], uc2);
        float q = exp2_hw(fmaxf(t1, t2));
        q = (af[e] > 0.f) ? q : 0.f;
        qsum += q; asum += af[e]; qv[e] = q;
      }
      unsigned qp[4], ap[4];
#pragma unroll
      for (int e = 0; e < 4; ++e) {
        qp[e] = pack_bf2(qv[2 * e], qv[2 * e + 1]);
        ap[e] = pack_bf2(af[2 * e], af[2 * e + 1]);
      }
      const s16x8 qa = __builtin_bit_cast(s16x8, *(uint4*)qp);
      const s16x8 aa = __builtin_bit_cast(s16x8, *(uint4*)ap);
#pragma unroll
      for (int dt = 0; dt < 8; ++dt) {
        const s16x8 b = *(const s16x8*)(bbufp + bOff + dt * 2048);
        acc1[dt] = __builtin_amdgcn_mfma_f32_16x16x32_bf16(qa, b, acc1[dt], 0, 0, 0);
        acc2[dt] = __builtin_amdgcn_mfma_f32_16x16x32_bf16(aa, b, acc2[dt], 0, 0, 0);
      }
      __syncthreads();  // consumers: no outstanding vmem -> free wait
      ab = (ab == 3) ? 0 : ab + 1;
      bb = (bb == 2) ? 0 : bb + 1;
    }

    // ---- stats ----
    qsum += __shfl_xor(qsum, 16, 64); qsum += __shfl_xor(qsum, 32, 64);
    asum += __shfl_xor(asum, 16, 64); asum += __shfl_xor(asum, 32, 64);
    if (dh == 0 && lane < 16) { sq[kh][rg][lane] = qsum; sa[kh][rg][lane] = asum; }
    __syncthreads();

    // ---- fold coef, reduce over kh via LDS (reuse sBM), write out ----
    f32x4 fin[8];
#pragma unroll
    for (int dt = 0; dt < 8; ++dt) {
#pragma unroll
      for (int g = 0; g < 4; ++g) {
        const int rr = kgrp * 4 + g;
        const float qq = sq[0][rg][rr] + sq[1][rg][rr];
        const float aa2 = sa[0][rg][rr] + sa[1][rg][rr];
        const float cfr = qq > 0.f ? 0.5f * aa2 / qq : 0.f;
        fin[dt][g] = cfr * acc1[dt][g] + 0.5f * acc2[dt][g];
      }
    }
    float* red = (float*)sBM;  // 48 KB reduce area
    const int rbase = ((rg * 2 + dh) * 8 * 64 + lane) * 4;
    if (kh == 1) {
#pragma unroll
      for (int dt = 0; dt < 8; ++dt) *(f32x4*)&red[rbase + dt * 256] = fin[dt];
    }
    __syncthreads();
    if (kh == 0) {
#pragma unroll
      for (int dt = 0; dt < 8; ++dt) {
        const f32x4 o = *(const f32x4*)&red[rbase + dt * 256];
        const int col = dh * 128 + dt * 16 + lrow;
#pragma unroll
        for (int g = 0; g < 4; ++g)
          out[(size_t)(i0 + rg * 16 + kgrp * 4 + g) * DD + col] = fin[dt][g] + o[g];
      }
    }
  } else if (w < 14) {
    // ============ ADJ PRODUCERS (waves 12,13): 4-deep, 7 ops/step ==========
    const int pid = w - 12;  // 0..1, owns adj ops idx = pid*6 .. pid*6+5
    const char* pA[6];
    int dA[6];
#pragma unroll
    for (int j = 0; j < 6; ++j) {
      const int idx = pid * 6 + j;
      pA[j] = (const char*)(adj + (size_t)(i0 + idx * 4 + (lane >> 4)) * NN)
              + (((lane & 15) ^ ((idx & 1) * 4 + (lane >> 4))) << 4);
      dA[j] = idx * 1024;
    }
    // v loaded redundantly by both adj waves (benign same-byte writes)
    const float* pV = v2 + lane;

    // prologue: stage adj+v for steps 0,1,2 (3 batches = 21 ops)
#pragma unroll
    for (int b = 0; b < 3; ++b) {
      char* nb = sAdjM + b * ABUFSZ;
#pragma unroll
      for (int j = 0; j < 6; ++j) { gl_lds16(pA[j], nb + dA[j]); pA[j] += 256; }
      gl_lds4(pV, nb + AVOFF); pV += 64;
    }
    asm volatile("s_waitcnt vmcnt(14)" ::: "memory");  // batch0 resident
    __builtin_amdgcn_s_barrier();

    int nb = 3;  // fill buffer (s+3)%4
    for (int s = 0; s < NSTEPS; ++s) {
      if (s <= NSTEPS - 4) {
        char* nbuf = sAdjM + nb * ABUFSZ;
#pragma unroll
        for (int j = 0; j < 6; ++j) { gl_lds16(pA[j], nbuf + dA[j]); pA[j] += 256; }
        gl_lds4(pV, nbuf + AVOFF); pV += 64;
        // need batch(s+1) done; batches (s+2),(s+3) in flight = 14 ops
        asm volatile("s_waitcnt vmcnt(14)" ::: "memory");
      } else if (s == NSTEPS - 3) {
        asm volatile("s_waitcnt vmcnt(7)" ::: "memory");   // (s+2) in flight
      } else if (s == NSTEPS - 2) {
        asm volatile("s_waitcnt vmcnt(0)" ::: "memory");   // all resident
      }
      __builtin_amdgcn_s_barrier();
      nb = (nb == 3) ? 0 : nb + 1;
    }
    __syncthreads();  // match stats barrier
    __syncthreads();  // match reduce barrier
  } else {
    // ============ B PRODUCERS (waves 14,15): 3-deep, 16 ops/step ===========
    const int pid = w - 14;  // 0..1, owns B ops ib = pid*16 .. pid*16+15
    const int ko = ((lane & 7) ^ (lane >> 3)) << 4;
    const char* pB[16];
    int dB[16];
#pragma unroll
    for (int j = 0; j < 16; ++j) {
      const int ib = pid * 16 + j;
      pB[j] = (const char*)h_poT + (size_t)(ib * 8 + (lane >> 3)) * (NN * 2) + ko;
      dB[j] = ib * 1024;
    }

    // prologue: stage B for steps 0,1 (2 batches = 32 ops)
#pragma unroll
    for (int b = 0; b < 2; ++b) {
      char* nbuf = sBM + b * BBUFSZ;
#pragma unroll
      for (int j = 0; j < 16; ++j) { gl_lds16(pB[j], nbuf + dB[j]); pB[j] += 128; }
    }
    asm volatile("s_waitcnt vmcnt(16)" ::: "memory");  // batch0 resident
    __builtin_amdgcn_s_barrier();

    int nb = 2;  // fill buffer (s+2)%3
    for (int s = 0; s < NSTEPS; ++s) {
      if (s <= NSTEPS - 3) {
        char* nbuf = sBM + nb * BBUFSZ;
#pragma unroll
        for (int j = 0; j < 16; ++j) { gl_lds16(pB[j], nbuf + dB[j]); pB[j] += 128; }
        // need B(s+1) done; B(s+2) in flight = 16 ops
        asm volatile("s_waitcnt vmcnt(16)" ::: "memory");
      } else if (s == NSTEPS - 2) {
        asm volatile("s_waitcnt vmcnt(0)" ::: "memory");   // final B resident
      }
      __builtin_amdgcn_s_barrier();
      nb = (nb == 2) ? 0 : nb + 1;
    }
    __syncthreads();  // match stats barrier
    __syncthreads();  // match reduce barrier
  }
}

// ---------------- fallback (small ws): round-2 proven kernel ----------------
__global__ __launch_bounds__(256) void fused_fb(
    const float* __restrict__ adj, const float* __restrict__ u,
    const float* __restrict__ v, const float* __restrict__ hpo,
    float* __restrict__ out) {
#define BMF 32
#define LDA 40
  __shared__ unsigned short qlds[BMF][LDA];
  __shared__ unsigned short alds[BMF][LDA];
  __shared__ unsigned short btf[DD][LDA];
  __shared__ float denom_s[BMF], deg_s[BMF], coef_s[BMF];

  const int t = threadIdx.x;
  const int wave = t >> 6, lane = t & 63;
  const int i0 = blockIdx.x * BMF;
  const int sr = t >> 3;
  const int sc = (t & 7) * 4;
  const float u_r = u[i0 + sr];
  const int d0 = wave * 64;
  const int lrow = lane & 15;
  const int kgrp = lane >> 4;

  f32x4 acc1[2][4] = {};
  f32x4 acc2[2][4] = {};
  float qsum = 0.f, asum = 0.f;

  const float* arow = adj + (size_t)(i0 + sr) * NN + sc;
  float4 a_cur = *(const float4*)(arow);

  constexpr int NSTEP = NN / 32;
  for (int jt = 0; jt < NSTEP; ++jt) {
    const int j = jt * 32;
    float4 a_nxt;
    const bool has_next = (jt + 1 < NSTEP);
    if (has_next) a_nxt = *(const float4*)(arow + j + 32);
    const float4 vv = *(const float4*)(v + j + sc);
    unsigned short qb[4], ab[4];
    {
      const float aa4[4] = {a_cur.x, a_cur.y, a_cur.z, a_cur.w};
      const float vvv[4] = {vv.x, vv.y, vv.z, vv.w};
#pragma unroll
      for (int k = 0; k < 4; ++k) {
        const float a = aa4[k];
        const float s = u_r + vvv[k];
        const float x = fmaxf(s, 0.01f * s);
        const float q = (a > 0.f) ? exp2_hw(x - SHIFT2) : 0.f;
        qsum += q;
        asum += a;
        qb[k] = f2bf(q);
        ab[k] = f2bf(a);
      }
    }
    *(uint2*)&qlds[sr][sc] = make_uint2((unsigned)qb[0] | ((unsigned)qb[1] << 16),
                                        (unsigned)qb[2] | ((unsigned)qb[3] << 16));
    *(uint2*)&alds[sr][sc] = make_uint2((unsigned)ab[0] | ((unsigned)ab[1] << 16),
                                        (unsigned)ab[2] | ((unsigned)ab[3] << 16));
    {
      const int br = t >> 3;
      const float* src = hpo + (size_t)(j + br) * DD;
#pragma unroll
      for (int cc = 0; cc < 8; ++cc) {
        const int c = (t & 7) * 4 + cc * 32;
        const float4 hv = *(const float4*)(src + c);
        btf[c + 0][br] = f2bf(hv.x);
        btf[c + 1][br] = f2bf(hv.y);
        btf[c + 2][br] = f2bf(hv.z);
        btf[c + 3][br] = f2bf(hv.w);
      }
    }
    __syncthreads();

    const s16x8 qa0 = *(const s16x8*)&qlds[lrow][kgrp * 8];
    const s16x8 qa1 = *(const s16x8*)&qlds[16 + lrow][kgrp * 8];
    const s16x8 ad0 = *(const s16x8*)&alds[lrow][kgrp * 8];
    const s16x8 ad1 = *(const s16x8*)&alds[16 + lrow][kgrp * 8];
#pragma unroll
    for (int dt = 0; dt < 4; ++dt) {
      const s16x8 b = *(const s16x8*)&btf[d0 + dt * 16 + lrow][kgrp * 8];
      acc1[0][dt] = __builtin_amdgcn_mfma_f32_16x16x32_bf16(qa0, b, acc1[0][dt], 0, 0, 0);
      acc1[1][dt] = __builtin_amdgcn_mfma_f32_16x16x32_bf16(qa1, b, acc1[1][dt], 0, 0, 0);
      acc2[0][dt] = __builtin_amdgcn_mfma_f32_16x16x32_bf16(ad0, b, acc2[0][dt], 0, 0, 0);
      acc2[1][dt] = __builtin_amdgcn_mfma_f32_16x16x32_bf16(ad1, b, acc2[1][dt], 0, 0, 0);
    }
    __syncthreads();
    if (has_next) a_cur = a_nxt;
  }
#pragma unroll
  for (int m = 1; m <= 4; m <<= 1) {
    qsum += __shfl_xor(qsum, m, 64);
    asum += __shfl_xor(asum, m, 64);
  }
  if ((t & 7) == 0) { denom_s[sr] = qsum; deg_s[sr] = asum; }
  __syncthreads();
  if (t < BMF) {
    const float dn = denom_s[t];
    coef_s[t] = dn > 0.f ? 0.5f * deg_s[t] / dn : 0.f;
  }
  __syncthreads();
#pragma unroll
  for (int f = 0; f < 2; ++f) {
#pragma unroll
    for (int dt = 0; dt < 4; ++dt) {
      const int col = d0 + dt * 16 + lrow;
#pragma unroll
      for (int g = 0; g < 4; ++g) {
        const int r = f * 16 + kgrp * 4 + g;
        out[(size_t)(i0 + r) * DD + col] =
            coef_s[r] * acc1[f][dt][g] + 0.5f * acc2[f][dt][g];
      }
    }
  }
}

extern "C" void kernel_launch(void* const* d_in, const int* in_sizes, int n_in,
                              void* d_out, int out_size, void* d_ws, size_t ws_size,
                              hipStream_t stream) {
  const float* h_eu = (const float*)d_in[0];
  const float* h_po = (const float*)d_in[1];
  const float* h_lo = (const float*)d_in[2];
  const float* adj  = (const float*)d_in[3];
  const float* a1   = (const float*)d_in[4];
  const float* a2   = (const float*)d_in[5];
  const float* a3   = (const float*)d_in[6];
  float* out = (float*)d_out;

  // ws layout: u[N] | v[N] | h_poT[D*N] bf16 = 6,389,760 B
  const size_t need_full = (size_t)2 * NN * 4 + (size_t)NN * DD * 2;
  float* u = (float*)d_ws;
  float* v = u + NN;
  unsigned short* h_poT = (unsigned short*)(v + NN);
  const bool big_ws = ws_size >= need_full;

  prep_uv<<<NN / 64, 256, 0, stream>>>(h_eu, h_po, h_lo, a1, a2, a3, u, v);
  if (big_ws) {
    prep_T<<<NN / 64, 256, 0, stream>>>(h_po, h_poT);
    fused18<<<NN / BM, 1024, 0, stream>>>(adj, u, v, h_poT, out);
  } else {
    fused_fb<<<NN / 32, 256, 0, stream>>>(adj, u, v, h_po, out);
  }
}